// Round 13
// baseline (638.537 us; speedup 1.0000x reference)
//
#include <hip/hip_runtime.h>
#include <cstdint>
#include <cstddef>

#define B_ 512
#define T_ 2048
#define D_ 64
#define H_ 48
#define C_ 3
#define LCH 16           // chunk length
#define KCH 128          // chunks per batch
#define NC  65536        // total chains = B_*KCH

#define RECON_FLOATS ((size_t)B_ * T_ * D_)            // 67,108,864 floats (output 0)
#define LOGIT_FLOATS ((size_t)B_ * C_)                 // 1536 floats      (output 1)
#define Z_OFF        (RECON_FLOATS + LOGIT_FLOATS)     // z region         (output 2)
// scratch inside the recon region (dec overwrites it LAST):
// u (std layout [b][t][48]) at 0 .. 50,331,648
#define S0_OFF   ((size_t)50331648)                    // S0[c][48]   (ms-space chunk-end, zero-init)
#define MIN_OFF  ((size_t)53477376)                    // M_in[c][48] (ms-space chunk-entry state)
#define ZP_OFF   ((size_t)56623104)                    // zsum_part[c][48]
#define A16_OFF  ((size_t)59768832)                    // A^16 row-major (2304 floats)
#define A_OFF    ((size_t)59771136)                    // A col-major [j*48+i] (2304 floats)

// ---------------- encoder GEMM (round-8 verbatim) ----------------
__global__ __launch_bounds__(128) void k_enc(
    const float* __restrict__ x, const float* __restrict__ Wenc,
    const float* __restrict__ benc, const float* __restrict__ bmem,
    float* __restrict__ out)
{
    __shared__ float sx[128][68];
    __shared__ float sw[48][68];
    __shared__ float sbe[48];

    const int tid = threadIdx.x;

    {
        const float4* wf4 = reinterpret_cast<const float4*>(Wenc);
        #pragma unroll
        for (int m = 0; m < 6; ++m) {
            const int idx = tid + 128 * m;
            const int c = idx >> 4, d4 = idx & 15;
            *reinterpret_cast<float4*>(&sw[c][d4 * 4]) = wf4[idx];
        }
    }
    if (tid < 48) sbe[tid] = benc[tid] + bmem[tid];

    {
        const float4* xf4 = reinterpret_cast<const float4*>(x) + (size_t)blockIdx.x * 2048;
        #pragma unroll
        for (int m = 0; m < 16; ++m) {
            const int idx = tid + 128 * m;
            const int row = idx >> 4, d4 = idx & 15;
            *reinterpret_cast<float4*>(&sx[row][d4 * 4]) = xf4[idx];
        }
    }
    __syncthreads();

    const int lane = tid & 63;
    const int wv   = tid >> 6;
    const int rg   = lane >> 2;
    const int cg   = lane & 3;
    const int rowb = wv * 64 + rg;
    const int colb = cg * 12;

    float acc[4][12];
    {
        float bia[12];
        #pragma unroll
        for (int m = 0; m < 3; ++m)
            *reinterpret_cast<float4*>(&bia[4 * m]) = *reinterpret_cast<const float4*>(&sbe[colb + 4 * m]);
        #pragma unroll
        for (int k = 0; k < 4; ++k)
            #pragma unroll
            for (int i = 0; i < 12; ++i) acc[k][i] = bia[i];
    }

    #pragma unroll 2
    for (int d4 = 0; d4 < 16; ++d4) {
        float4 xf[4];
        #pragma unroll
        for (int k = 0; k < 4; ++k)
            xf[k] = *reinterpret_cast<const float4*>(&sx[rowb + 16 * k][d4 * 4]);
        #pragma unroll
        for (int i = 0; i < 12; ++i) {
            const float4 wvv = *reinterpret_cast<const float4*>(&sw[colb + i][d4 * 4]);
            #pragma unroll
            for (int k = 0; k < 4; ++k)
                acc[k][i] = fmaf(xf[k].x, wvv.x, fmaf(xf[k].y, wvv.y,
                             fmaf(xf[k].z, wvv.z, fmaf(xf[k].w, wvv.w, acc[k][i]))));
        }
    }

    const size_t row0 = (size_t)blockIdx.x * 128 + rowb;
    #pragma unroll
    for (int k = 0; k < 4; ++k) {
        float* dst = out + (row0 + 16 * k) * 48 + colb;
        #pragma unroll
        for (int m = 0; m < 3; ++m)
            *reinterpret_cast<float4*>(dst + 4 * m) =
                make_float4(acc[k][4 * m], acc[k][4 * m + 1], acc[k][4 * m + 2], acc[k][4 * m + 3]);
    }
}

// ---------------- A (col-major stash) + A^16 via 4 squarings ----------------
__global__ __launch_bounds__(576) void k_powA(
    const float* __restrict__ Wmem, float* __restrict__ out)
{
    __shared__ float a0[48 * 49];
    __shared__ float a1[48 * 49];
    const int tid = threadIdx.x;

    for (int idx = tid; idx < 2304; idx += 576) {
        const int i = idx / 48, j = idx - i * 48;
        a0[i * 49 + j] = 0.1f * Wmem[idx] + (i == j ? 0.9f : 0.0f);
    }
    __syncthreads();

    // stash A col-major: Acm[j*48+i] = A[i][j]
    for (int idx = tid; idx < 2304; idx += 576) {
        const int i = idx / 48, j = idx - i * 48;
        out[A_OFF + j * 48 + i] = a0[i * 49 + j];
    }

    float* src = a0;
    float* dst = a1;
    #pragma unroll 1
    for (int it = 0; it < 4; ++it) {
        float v[4];
        #pragma unroll
        for (int q = 0; q < 4; ++q) {
            const int o = tid + 576 * q;
            const int i = o / 48, j = o - i * 48;
            float acc = 0.f;
            #pragma unroll
            for (int k = 0; k < 48; ++k)
                acc = fmaf(src[i * 49 + k], src[k * 49 + j], acc);
            v[q] = acc;
        }
        #pragma unroll
        for (int q = 0; q < 4; ++q) {
            const int o = tid + 576 * q;
            const int i = o / 48, j = o - i * 48;
            dst[i * 49 + j] = v[q];
        }
        __syncthreads();
        float* t = src; src = dst; dst = t;
    }
    for (int idx = tid; idx < 2304; idx += 576) {
        const int i = idx / 48, j = idx - i * 48;
        out[A16_OFF + idx] = src[i * 49 + j];
    }
}

// static component select (j must be a compile-time-unrolled index)
#define MO_COMP(j) ((j & 3) == 0 ? mo[(j) >> 2].x : (j & 3) == 1 ? mo[(j) >> 2].y \
                   : (j & 3) == 2 ? mo[(j) >> 2].z : mo[(j) >> 2].w)

// ---------------- phase 1: chunk-end states from zero; chain-per-lane, A via SGPRs ----------------
__global__ __launch_bounds__(64) void k_p1(
    const float* __restrict__ Acm,    // A col-major [j*48+i] (disjoint region)
    const float* __restrict__ u,      // u[c*768]              (disjoint region)
    float* __restrict__ s0)           // S0[c*48]              (disjoint region)
{
    const int lane = threadIdx.x;
    const size_t c = (size_t)blockIdx.x * 64 + lane;
    const float4* ub4 = reinterpret_cast<const float4*>(u + c * 768);

    float4 mo[12];
    #pragma unroll
    for (int q = 0; q < 12; ++q) mo[q] = make_float4(0.f, 0.f, 0.f, 0.f);

    #pragma unroll 1
    for (int s = 0; s < LCH; ++s) {
        asm volatile("" ::: "memory");   // step fence: A reloads per step (no 2304-SGPR hoist)
        float4 uu[12];
        #pragma unroll
        for (int q = 0; q < 12; ++q) uu[q] = ub4[s * 12 + q];   // issued early, used at step end
        float4 acc[12];
        #pragma unroll
        for (int q = 0; q < 12; ++q) acc[q] = make_float4(0.f, 0.f, 0.f, 0.f);
        #pragma unroll
        for (int j = 0; j < 48; ++j) {
            const float mj = MO_COMP(j);
            const float* colp = Acm + j * 48;    // wave-uniform -> s_load, SGPR operand in fma
            #pragma unroll
            for (int q = 0; q < 12; ++q) {
                acc[q].x = fmaf(colp[4 * q + 0], mj, acc[q].x);
                acc[q].y = fmaf(colp[4 * q + 1], mj, acc[q].y);
                acc[q].z = fmaf(colp[4 * q + 2], mj, acc[q].z);
                acc[q].w = fmaf(colp[4 * q + 3], mj, acc[q].w);
            }
        }
        #pragma unroll
        for (int q = 0; q < 12; ++q) {
            mo[q].x = acc[q].x + uu[q].x;
            mo[q].y = acc[q].y + uu[q].y;
            mo[q].z = acc[q].z + uu[q].z;
            mo[q].w = acc[q].w + uu[q].w;
        }
    }

    float4* dst = reinterpret_cast<float4*>(s0 + c * 48);
    #pragma unroll
    for (int q = 0; q < 12; ++q) dst[q] = mo[q];
}

// ---------------- phase 2: sequential boundary combine per batch (r11 verbatim) ----------------
__global__ __launch_bounds__(64) void k_p2(float* __restrict__ out)
{
    const int lane = threadIdx.x;
    const int b    = blockIdx.x;
    const int h    = lane < H_ ? lane : 0;

    const float* A16 = out + A16_OFF;
    float w16[48];
    #pragma unroll
    for (int j = 0; j < 48; ++j) w16[j] = A16[h * 48 + j];

    float E = 0.f;
    float s0 = out[S0_OFF + (((size_t)b << 7) | 0) * 48 + h];
    #pragma unroll 1
    for (int k = 0; k < KCH; ++k) {
        const size_t c = ((size_t)b << 7) | k;
        if (lane < H_) out[MIN_OFF + c * 48 + h] = E;
        float a0 = s0, a1 = 0.f, a2 = 0.f, a3 = 0.f, a4 = 0.f, a5 = 0.f, a6 = 0.f, a7 = 0.f;
        if (k + 1 < KCH) s0 = out[S0_OFF + (c + 1) * 48 + h];
        #pragma unroll
        for (int g = 0; g < 6; ++g) {
            const int j = 8 * g;
            const float m0 = __int_as_float(__builtin_amdgcn_readlane(__float_as_int(E), j + 0));
            const float m1 = __int_as_float(__builtin_amdgcn_readlane(__float_as_int(E), j + 1));
            const float m2 = __int_as_float(__builtin_amdgcn_readlane(__float_as_int(E), j + 2));
            const float m3 = __int_as_float(__builtin_amdgcn_readlane(__float_as_int(E), j + 3));
            const float m4 = __int_as_float(__builtin_amdgcn_readlane(__float_as_int(E), j + 4));
            const float m5 = __int_as_float(__builtin_amdgcn_readlane(__float_as_int(E), j + 5));
            const float m6 = __int_as_float(__builtin_amdgcn_readlane(__float_as_int(E), j + 6));
            const float m7 = __int_as_float(__builtin_amdgcn_readlane(__float_as_int(E), j + 7));
            a0 = fmaf(m0, w16[j + 0], a0);
            a1 = fmaf(m1, w16[j + 1], a1);
            a2 = fmaf(m2, w16[j + 2], a2);
            a3 = fmaf(m3, w16[j + 3], a3);
            a4 = fmaf(m4, w16[j + 4], a4);
            a5 = fmaf(m5, w16[j + 5], a5);
            a6 = fmaf(m6, w16[j + 6], a6);
            a7 = fmaf(m7, w16[j + 7], a7);
        }
        E = ((a0 + a1) + (a2 + a3)) + ((a4 + a5) + (a6 + a7));
    }
}

// ---------------- phase 3: re-run chunks from corrected starts; chain-per-lane, A via SGPRs ----------------
__global__ __launch_bounds__(64) void k_p3(
    const float* __restrict__ Acm,    // A col-major
    const float* __restrict__ u,      // u[c*768]
    const float* __restrict__ min_,   // M_in[c*48]
    float* __restrict__ z,            // z[c*768]
    float* __restrict__ zp)           // zsum_part[c*48]
{
    const int lane = threadIdx.x;
    const size_t c = (size_t)blockIdx.x * 64 + lane;
    const float4* ub4 = reinterpret_cast<const float4*>(u + c * 768);
    float4*       zb4 = reinterpret_cast<float4*>(z + c * 768);

    float4 mo[12], zsum[12];
    {
        const float4* m4 = reinterpret_cast<const float4*>(min_ + c * 48);
        #pragma unroll
        for (int q = 0; q < 12; ++q) mo[q] = m4[q];
    }
    #pragma unroll
    for (int q = 0; q < 12; ++q) zsum[q] = make_float4(0.f, 0.f, 0.f, 0.f);

    const float kExp = -0.14426950408889634f;   // -0.1*log2(e): z = sigmoid(ms/10)

    #pragma unroll 1
    for (int s = 0; s < LCH; ++s) {
        asm volatile("" ::: "memory");
        float4 uu[12];
        #pragma unroll
        for (int q = 0; q < 12; ++q) uu[q] = ub4[s * 12 + q];
        float4 acc[12];
        #pragma unroll
        for (int q = 0; q < 12; ++q) acc[q] = make_float4(0.f, 0.f, 0.f, 0.f);
        #pragma unroll
        for (int j = 0; j < 48; ++j) {
            const float mj = MO_COMP(j);
            const float* colp = Acm + j * 48;
            #pragma unroll
            for (int q = 0; q < 12; ++q) {
                acc[q].x = fmaf(colp[4 * q + 0], mj, acc[q].x);
                acc[q].y = fmaf(colp[4 * q + 1], mj, acc[q].y);
                acc[q].z = fmaf(colp[4 * q + 2], mj, acc[q].z);
                acc[q].w = fmaf(colp[4 * q + 3], mj, acc[q].w);
            }
        }
        #pragma unroll
        for (int q = 0; q < 12; ++q) {
            mo[q].x = acc[q].x + uu[q].x;
            mo[q].y = acc[q].y + uu[q].y;
            mo[q].z = acc[q].z + uu[q].z;
            mo[q].w = acc[q].w + uu[q].w;
        }
        // z = sigmoid(mo/10): store + accumulate
        #pragma unroll
        for (int q = 0; q < 12; ++q) {
            float4 zq;
            zq.x = __builtin_amdgcn_rcpf(1.0f + __builtin_amdgcn_exp2f(mo[q].x * kExp));
            zq.y = __builtin_amdgcn_rcpf(1.0f + __builtin_amdgcn_exp2f(mo[q].y * kExp));
            zq.z = __builtin_amdgcn_rcpf(1.0f + __builtin_amdgcn_exp2f(mo[q].z * kExp));
            zq.w = __builtin_amdgcn_rcpf(1.0f + __builtin_amdgcn_exp2f(mo[q].w * kExp));
            zsum[q].x += zq.x; zsum[q].y += zq.y; zsum[q].z += zq.z; zsum[q].w += zq.w;
            zb4[s * 12 + q] = zq;
        }
    }

    float4* zpd = reinterpret_cast<float4*>(zp + c * 48);
    #pragma unroll
    for (int q = 0; q < 12; ++q) zpd[q] = zsum[q];
}

// ---------------- classifier: reduce zsum partials, logits ----------------
__global__ __launch_bounds__(64) void k_cls(
    const float* __restrict__ Wcls, const float* __restrict__ bcls,
    float* __restrict__ out)
{
    __shared__ float sz[48];
    const int lane = threadIdx.x;
    const int b    = blockIdx.x;
    if (lane < 48) {
        float acc = 0.f;
        #pragma unroll 4
        for (int k = 0; k < KCH; ++k)
            acc += out[ZP_OFF + (((size_t)b << 7) | k) * 48 + lane];
        sz[lane] = acc;
    }
    __syncthreads();
    if (lane < C_) {
        float acc = 0.f;
        #pragma unroll
        for (int h = 0; h < 48; ++h) acc = fmaf(sz[h], Wcls[lane * 48 + h], acc);
        out[RECON_FLOATS + (size_t)b * C_ + lane] = acc * (1.0f / (float)T_) + bcls[lane];
    }
}

// ---------------- decoder GEMM (round-8 verbatim) ----------------
__global__ __launch_bounds__(256) void k_dec(
    const float* __restrict__ Wdec, const float* __restrict__ bdec,
    float* __restrict__ out)
{
    __shared__ float sz[256][52];
    __shared__ float swT[48][68];
    __shared__ float sbd[64];

    const int tid = threadIdx.x;

    #pragma unroll
    for (int m = 0; m < 12; ++m) {
        const int idx = tid + 256 * m;
        const int d = idx / 48, hh = idx - d * 48;
        swT[hh][d] = Wdec[idx];
    }
    if (tid < 64) sbd[tid] = bdec[tid];

    {
        const float4* zf4 = reinterpret_cast<const float4*>(out + Z_OFF) + (size_t)blockIdx.x * 3072;
        #pragma unroll
        for (int m = 0; m < 12; ++m) {
            const int idx = tid + 256 * m;
            const int row = idx / 12, c4 = idx - row * 12;
            *reinterpret_cast<float4*>(&sz[row][c4 * 4]) = zf4[idx];
        }
    }
    __syncthreads();

    const int lane = tid & 63;
    const int wv   = tid >> 6;
    const int rg   = lane >> 3;
    const int cg   = lane & 7;
    const int rowb = wv * 64 + rg;
    const int colb = cg * 8;

    float acc[8][8];
    {
        float bd[8];
        *reinterpret_cast<float4*>(&bd[0]) = *reinterpret_cast<const float4*>(&sbd[colb]);
        *reinterpret_cast<float4*>(&bd[4]) = *reinterpret_cast<const float4*>(&sbd[colb + 4]);
        #pragma unroll
        for (int k = 0; k < 8; ++k)
            #pragma unroll
            for (int c = 0; c < 8; ++c) acc[k][c] = bd[c];
    }

    #pragma unroll 2
    for (int h4 = 0; h4 < 12; ++h4) {
        float4 zf[8];
        #pragma unroll
        for (int k = 0; k < 8; ++k)
            zf[k] = *reinterpret_cast<const float4*>(&sz[rowb + 8 * k][h4 * 4]);
        #pragma unroll
        for (int j = 0; j < 4; ++j) {
            const float4 w0 = *reinterpret_cast<const float4*>(&swT[h4 * 4 + j][colb]);
            const float4 w1 = *reinterpret_cast<const float4*>(&swT[h4 * 4 + j][colb + 4]);
            #pragma unroll
            for (int k = 0; k < 8; ++k) {
                const float zv = j == 0 ? zf[k].x : (j == 1 ? zf[k].y : (j == 2 ? zf[k].z : zf[k].w));
                acc[k][0] = fmaf(zv, w0.x, acc[k][0]);
                acc[k][1] = fmaf(zv, w0.y, acc[k][1]);
                acc[k][2] = fmaf(zv, w0.z, acc[k][2]);
                acc[k][3] = fmaf(zv, w0.w, acc[k][3]);
                acc[k][4] = fmaf(zv, w1.x, acc[k][4]);
                acc[k][5] = fmaf(zv, w1.y, acc[k][5]);
                acc[k][6] = fmaf(zv, w1.z, acc[k][6]);
                acc[k][7] = fmaf(zv, w1.w, acc[k][7]);
            }
        }
    }

    const size_t row0 = (size_t)blockIdx.x * 256 + rowb;
    #pragma unroll
    for (int k = 0; k < 8; ++k) {
        float* dst = out + (row0 + 8 * k) * 64 + colb;
        *reinterpret_cast<float4*>(dst)     = make_float4(acc[k][0], acc[k][1], acc[k][2], acc[k][3]);
        *reinterpret_cast<float4*>(dst + 4) = make_float4(acc[k][4], acc[k][5], acc[k][6], acc[k][7]);
    }
}

extern "C" void kernel_launch(void* const* d_in, const int* in_sizes, int n_in,
                              void* d_out, int out_size, void* d_ws, size_t ws_size,
                              hipStream_t stream) {
    const float* x    = (const float*)d_in[0];
    const float* Wenc = (const float*)d_in[1];
    const float* benc = (const float*)d_in[2];
    const float* Wmem = (const float*)d_in[3];
    const float* bmem = (const float*)d_in[4];
    const float* Wdec = (const float*)d_in[5];
    const float* bdec = (const float*)d_in[6];
    const float* Wcls = (const float*)d_in[7];
    const float* bcls = (const float*)d_in[8];
    float* out = (float*)d_out;

    k_powA<<<dim3(1), dim3(576), 0, stream>>>(Wmem, out);
    k_enc<<<dim3((B_ * T_) / 128), dim3(128), 0, stream>>>(x, Wenc, benc, bmem, out);
    k_p1<<<dim3(NC / 64), dim3(64), 0, stream>>>(out + A_OFF, out, out + S0_OFF);
    k_p2<<<dim3(B_), dim3(64), 0, stream>>>(out);
    k_p3<<<dim3(NC / 64), dim3(64), 0, stream>>>(out + A_OFF, out, out + MIN_OFF,
                                                 out + Z_OFF, out + ZP_OFF);
    k_cls<<<dim3(B_), dim3(64), 0, stream>>>(Wcls, bcls, out);
    k_dec<<<dim3((B_ * T_) / 256), dim3(256), 0, stream>>>(Wdec, bdec, out);
}

// Round 14
// 586.110 us; speedup vs baseline: 1.0894x; 1.0894x over previous
//
#include <hip/hip_runtime.h>
#include <cstdint>
#include <cstddef>

#define B_ 512
#define T_ 2048
#define D_ 64
#define H_ 48
#define C_ 3
#define LCH 16           // chunk length
#define KCH 128          // chunks per batch
#define NC  65536        // total chains = B_*KCH
#define CPB 128          // chains per p1/p3 block

#define RECON_FLOATS ((size_t)B_ * T_ * D_)            // 67,108,864 floats (output 0)
#define LOGIT_FLOATS ((size_t)B_ * C_)                 // 1536 floats      (output 1)
#define Z_OFF        (RECON_FLOATS + LOGIT_FLOATS)     // z region         (output 2)
// scratch inside the recon region (dec overwrites it LAST):
// u (std layout [b][t][48]) at 0 .. 50,331,648
#define S0_OFF   ((size_t)50331648)                    // S0[c][48]
#define MIN_OFF  ((size_t)53477376)                    // M_in[c][48]
#define A16_OFF  ((size_t)59768832)                    // A^16 row-major (2304 floats)

// ---------------- encoder GEMM (round-8 verbatim) ----------------
__global__ __launch_bounds__(128) void k_enc(
    const float* __restrict__ x, const float* __restrict__ Wenc,
    const float* __restrict__ benc, const float* __restrict__ bmem,
    float* __restrict__ out)
{
    __shared__ float sx[128][68];
    __shared__ float sw[48][68];
    __shared__ float sbe[48];

    const int tid = threadIdx.x;

    {
        const float4* wf4 = reinterpret_cast<const float4*>(Wenc);
        #pragma unroll
        for (int m = 0; m < 6; ++m) {
            const int idx = tid + 128 * m;
            const int c = idx >> 4, d4 = idx & 15;
            *reinterpret_cast<float4*>(&sw[c][d4 * 4]) = wf4[idx];
        }
    }
    if (tid < 48) sbe[tid] = benc[tid] + bmem[tid];

    {
        const float4* xf4 = reinterpret_cast<const float4*>(x) + (size_t)blockIdx.x * 2048;
        #pragma unroll
        for (int m = 0; m < 16; ++m) {
            const int idx = tid + 128 * m;
            const int row = idx >> 4, d4 = idx & 15;
            *reinterpret_cast<float4*>(&sx[row][d4 * 4]) = xf4[idx];
        }
    }
    __syncthreads();

    const int lane = tid & 63;
    const int wv   = tid >> 6;
    const int rg   = lane >> 2;
    const int cg   = lane & 3;
    const int rowb = wv * 64 + rg;
    const int colb = cg * 12;

    float acc[4][12];
    {
        float bia[12];
        #pragma unroll
        for (int m = 0; m < 3; ++m)
            *reinterpret_cast<float4*>(&bia[4 * m]) = *reinterpret_cast<const float4*>(&sbe[colb + 4 * m]);
        #pragma unroll
        for (int k = 0; k < 4; ++k)
            #pragma unroll
            for (int i = 0; i < 12; ++i) acc[k][i] = bia[i];
    }

    #pragma unroll 2
    for (int d4 = 0; d4 < 16; ++d4) {
        float4 xf[4];
        #pragma unroll
        for (int k = 0; k < 4; ++k)
            xf[k] = *reinterpret_cast<const float4*>(&sx[rowb + 16 * k][d4 * 4]);
        #pragma unroll
        for (int i = 0; i < 12; ++i) {
            const float4 wvv = *reinterpret_cast<const float4*>(&sw[colb + i][d4 * 4]);
            #pragma unroll
            for (int k = 0; k < 4; ++k)
                acc[k][i] = fmaf(xf[k].x, wvv.x, fmaf(xf[k].y, wvv.y,
                             fmaf(xf[k].z, wvv.z, fmaf(xf[k].w, wvv.w, acc[k][i]))));
        }
    }

    const size_t row0 = (size_t)blockIdx.x * 128 + rowb;
    #pragma unroll
    for (int k = 0; k < 4; ++k) {
        float* dst = out + (row0 + 16 * k) * 48 + colb;
        #pragma unroll
        for (int m = 0; m < 3; ++m)
            *reinterpret_cast<float4*>(dst + 4 * m) =
                make_float4(acc[k][4 * m], acc[k][4 * m + 1], acc[k][4 * m + 2], acc[k][4 * m + 3]);
    }
}

// ---------------- A^16 via 4 squarings (r12 verbatim) ----------------
__global__ __launch_bounds__(576) void k_powA(
    const float* __restrict__ Wmem, float* __restrict__ out)
{
    __shared__ float a0[48 * 49];
    __shared__ float a1[48 * 49];
    const int tid = threadIdx.x;

    for (int idx = tid; idx < 2304; idx += 576) {
        const int i = idx / 48, j = idx - i * 48;
        a0[i * 49 + j] = 0.1f * Wmem[idx] + (i == j ? 0.9f : 0.0f);
    }
    __syncthreads();

    float* src = a0;
    float* dst = a1;
    #pragma unroll 1
    for (int it = 0; it < 4; ++it) {
        float v[4];
        #pragma unroll
        for (int q = 0; q < 4; ++q) {
            const int o = tid + 576 * q;
            const int i = o / 48, j = o - i * 48;
            float acc = 0.f;
            #pragma unroll
            for (int k = 0; k < 48; ++k)
                acc = fmaf(src[i * 49 + k], src[k * 49 + j], acc);
            v[q] = acc;
        }
        #pragma unroll
        for (int q = 0; q < 4; ++q) {
            const int o = tid + 576 * q;
            const int i = o / 48, j = o - i * 48;
            dst[i * 49 + j] = v[q];
        }
        __syncthreads();
        float* t = src; src = dst; dst = t;
    }
    for (int idx = tid; idx < 2304; idx += 576) {
        const int i = idx / 48, j = idx - i * 48;
        out[A16_OFF + idx] = src[i * 49 + j];
    }
}

// shared pieces for the iterated-GEMM scan kernels:
// thread tile 6 rows x 8 chains; 128 threads = 8 rowg x 16 colg; M[48][132], A[48][52]
#define SCAN_PROLOG                                                             \
    const int tid  = threadIdx.x;                                               \
    for (int idx = tid; idx < 2304; idx += 128) {                               \
        const int i = idx / 48, j = idx - i * 48;                               \
        sA[i * 52 + j] = 0.1f * Wmem[idx] + (i == j ? 0.9f : 0.0f);             \
    }                                                                           \
    const int rowg  = tid >> 4;          /* 0..7  */                            \
    const int colg  = tid & 15;          /* 0..15 */                            \
    const int r0    = rowg * 6;                                                 \
    const int cbase = colg * 8;                                                 \
    const size_t c0 = (size_t)blockIdx.x * CPB;

#define LOAD_UREG(sidx)                                                         \
    {                                                                           \
        const float* pb = u + (c0 + cbase) * 768 + (size_t)(sidx) * 48 + r0;    \
        _Pragma("unroll")                                                       \
        for (int j = 0; j < 8; ++j) {                                           \
            _Pragma("unroll")                                                   \
            for (int e = 0; e < 3; ++e) {                                       \
                const float2 v = *reinterpret_cast<const float2*>(pb + j * 768 + 2 * e); \
                ureg[j][2 * e] = v.x; ureg[j][2 * e + 1] = v.y;                 \
            }                                                                   \
        }                                                                       \
    }

#define GEMM_STEP                                                               \
    float acc[6][8];                                                            \
    _Pragma("unroll")                                                           \
    for (int r = 0; r < 6; ++r)                                                 \
        _Pragma("unroll")                                                       \
        for (int j = 0; j < 8; ++j) acc[r][j] = ureg[j][r];                     \
    LOAD_UREG(s + 1 < LCH ? s + 1 : LCH - 1)                                    \
    _Pragma("unroll 2")                                                         \
    for (int k4 = 0; k4 < 12; ++k4) {                                           \
        float4 av[6];                                                           \
        _Pragma("unroll")                                                       \
        for (int r = 0; r < 6; ++r)                                             \
            av[r] = *reinterpret_cast<const float4*>(&sA[(r0 + r) * 52 + k4 * 4]); \
        float4 mv0[4], mv1[4];                                                  \
        _Pragma("unroll")                                                       \
        for (int kk = 0; kk < 4; ++kk) {                                        \
            mv0[kk] = *reinterpret_cast<const float4*>(&sM[(k4 * 4 + kk) * 132 + cbase]);     \
            mv1[kk] = *reinterpret_cast<const float4*>(&sM[(k4 * 4 + kk) * 132 + cbase + 4]); \
        }                                                                       \
        _Pragma("unroll")                                                       \
        for (int kk = 0; kk < 4; ++kk) {                                        \
            _Pragma("unroll")                                                   \
            for (int r = 0; r < 6; ++r) {                                       \
                const float a = kk == 0 ? av[r].x : kk == 1 ? av[r].y           \
                              : kk == 2 ? av[r].z : av[r].w;                    \
                acc[r][0] = fmaf(a, mv0[kk].x, acc[r][0]);                      \
                acc[r][1] = fmaf(a, mv0[kk].y, acc[r][1]);                      \
                acc[r][2] = fmaf(a, mv0[kk].z, acc[r][2]);                      \
                acc[r][3] = fmaf(a, mv0[kk].w, acc[r][3]);                      \
                acc[r][4] = fmaf(a, mv1[kk].x, acc[r][4]);                      \
                acc[r][5] = fmaf(a, mv1[kk].y, acc[r][5]);                      \
                acc[r][6] = fmaf(a, mv1[kk].z, acc[r][6]);                      \
                acc[r][7] = fmaf(a, mv1[kk].w, acc[r][7]);                      \
            }                                                                   \
        }                                                                       \
    }

#define WRITE_M                                                                 \
    __syncthreads();                                                            \
    _Pragma("unroll")                                                           \
    for (int r = 0; r < 6; ++r) {                                               \
        *reinterpret_cast<float4*>(&sM[(r0 + r) * 132 + cbase]) =               \
            make_float4(acc[r][0], acc[r][1], acc[r][2], acc[r][3]);            \
        *reinterpret_cast<float4*>(&sM[(r0 + r) * 132 + cbase + 4]) =           \
            make_float4(acc[r][4], acc[r][5], acc[r][6], acc[r][7]);            \
    }                                                                           \
    __syncthreads();

// ---------------- phase 1: chunk-end states from zero (iterated block GEMM) ----------------
__global__ __launch_bounds__(128) void k_p1(
    const float* __restrict__ Wmem, const float* __restrict__ u,
    float* __restrict__ s0out)
{
    __shared__ float sA[48 * 52];
    __shared__ float sM[48 * 132];
    SCAN_PROLOG
    for (int idx = tid; idx < 48 * 132; idx += 128) sM[idx] = 0.f;

    float ureg[8][6];
    LOAD_UREG(0)
    __syncthreads();

    #pragma unroll 1
    for (int s = 0; s < LCH; ++s) {
        GEMM_STEP
        WRITE_M
    }

    for (int idx = tid; idx < 48 * CPB; idx += 128) {
        const int c = idx / 48, h = idx - c * 48;
        s0out[(c0 + c) * 48 + h] = sM[h * 132 + c];
    }
}

// ---------------- phase 2: sequential boundary combine per batch (r11 verbatim) ----------------
__global__ __launch_bounds__(64) void k_p2(float* __restrict__ out)
{
    const int lane = threadIdx.x;
    const int b    = blockIdx.x;
    const int h    = lane < H_ ? lane : 0;

    const float* A16 = out + A16_OFF;
    float w16[48];
    #pragma unroll
    for (int j = 0; j < 48; ++j) w16[j] = A16[h * 48 + j];

    float E = 0.f;
    float s0 = out[S0_OFF + (((size_t)b << 7) | 0) * 48 + h];
    #pragma unroll 1
    for (int k = 0; k < KCH; ++k) {
        const size_t c = ((size_t)b << 7) | k;
        if (lane < H_) out[MIN_OFF + c * 48 + h] = E;
        float a0 = s0, a1 = 0.f, a2 = 0.f, a3 = 0.f, a4 = 0.f, a5 = 0.f, a6 = 0.f, a7 = 0.f;
        if (k + 1 < KCH) s0 = out[S0_OFF + (c + 1) * 48 + h];
        #pragma unroll
        for (int g = 0; g < 6; ++g) {
            const int j = 8 * g;
            const float m0 = __int_as_float(__builtin_amdgcn_readlane(__float_as_int(E), j + 0));
            const float m1 = __int_as_float(__builtin_amdgcn_readlane(__float_as_int(E), j + 1));
            const float m2 = __int_as_float(__builtin_amdgcn_readlane(__float_as_int(E), j + 2));
            const float m3 = __int_as_float(__builtin_amdgcn_readlane(__float_as_int(E), j + 3));
            const float m4 = __int_as_float(__builtin_amdgcn_readlane(__float_as_int(E), j + 4));
            const float m5 = __int_as_float(__builtin_amdgcn_readlane(__float_as_int(E), j + 5));
            const float m6 = __int_as_float(__builtin_amdgcn_readlane(__float_as_int(E), j + 6));
            const float m7 = __int_as_float(__builtin_amdgcn_readlane(__float_as_int(E), j + 7));
            a0 = fmaf(m0, w16[j + 0], a0);
            a1 = fmaf(m1, w16[j + 1], a1);
            a2 = fmaf(m2, w16[j + 2], a2);
            a3 = fmaf(m3, w16[j + 3], a3);
            a4 = fmaf(m4, w16[j + 4], a4);
            a5 = fmaf(m5, w16[j + 5], a5);
            a6 = fmaf(m6, w16[j + 6], a6);
            a7 = fmaf(m7, w16[j + 7], a7);
        }
        E = ((a0 + a1) + (a2 + a3)) + ((a4 + a5) + (a6 + a7));
    }
}

// ---------------- phase 3: re-run chunks from corrected starts; emit z ----------------
__global__ __launch_bounds__(128) void k_p3(
    const float* __restrict__ Wmem, const float* __restrict__ u,
    const float* __restrict__ min_, float* __restrict__ z)
{
    __shared__ float sA[48 * 52];
    __shared__ float sM[48 * 132];
    SCAN_PROLOG
    for (int idx = tid; idx < 48 * CPB; idx += 128) {
        const int c = idx / 48, h = idx - c * 48;
        sM[h * 132 + c] = min_[(c0 + c) * 48 + h];
    }

    float ureg[8][6];
    LOAD_UREG(0)
    __syncthreads();

    const float kExp = -0.14426950408889634f;   // -0.1*log2(e): z = sigmoid(ms/10)

    #pragma unroll 1
    for (int s = 0; s < LCH; ++s) {
        GEMM_STEP
        // z = sigmoid(acc/10) -> global (std layout)
        {
            float* zb = z + (c0 + cbase) * 768 + (size_t)s * 48 + r0;
            #pragma unroll
            for (int j = 0; j < 8; ++j) {
                float zq[6];
                #pragma unroll
                for (int r = 0; r < 6; ++r)
                    zq[r] = __builtin_amdgcn_rcpf(1.0f + __builtin_amdgcn_exp2f(acc[r][j] * kExp));
                #pragma unroll
                for (int e = 0; e < 3; ++e)
                    *reinterpret_cast<float2*>(zb + j * 768 + 2 * e) = make_float2(zq[2 * e], zq[2 * e + 1]);
            }
        }
        WRITE_M
    }
}

// ---------------- classifier: sum z over t directly, then logits ----------------
__global__ __launch_bounds__(64) void k_cls(
    const float* __restrict__ Wcls, const float* __restrict__ bcls,
    float* __restrict__ out)
{
    __shared__ float sz[48];
    const int lane = threadIdx.x;
    const int b    = blockIdx.x;
    const float* zb = out + Z_OFF + (size_t)b * T_ * 48;

    if (lane < 48) {
        float a0 = 0.f, a1 = 0.f, a2 = 0.f, a3 = 0.f;
        #pragma unroll 1
        for (int t = 0; t < T_; t += 32) {
            #pragma unroll
            for (int i = 0; i < 32; i += 4) {
                a0 += zb[(size_t)(t + i + 0) * 48 + lane];
                a1 += zb[(size_t)(t + i + 1) * 48 + lane];
                a2 += zb[(size_t)(t + i + 2) * 48 + lane];
                a3 += zb[(size_t)(t + i + 3) * 48 + lane];
            }
        }
        sz[lane] = (a0 + a1) + (a2 + a3);
    }
    __syncthreads();
    if (lane < C_) {
        float acc = 0.f;
        #pragma unroll
        for (int h = 0; h < 48; ++h) acc = fmaf(sz[h], Wcls[lane * 48 + h], acc);
        out[RECON_FLOATS + (size_t)b * C_ + lane] = acc * (1.0f / (float)T_) + bcls[lane];
    }
}

// ---------------- decoder GEMM (round-8 verbatim) ----------------
__global__ __launch_bounds__(256) void k_dec(
    const float* __restrict__ Wdec, const float* __restrict__ bdec,
    float* __restrict__ out)
{
    __shared__ float sz[256][52];
    __shared__ float swT[48][68];
    __shared__ float sbd[64];

    const int tid = threadIdx.x;

    #pragma unroll
    for (int m = 0; m < 12; ++m) {
        const int idx = tid + 256 * m;
        const int d = idx / 48, hh = idx - d * 48;
        swT[hh][d] = Wdec[idx];
    }
    if (tid < 64) sbd[tid] = bdec[tid];

    {
        const float4* zf4 = reinterpret_cast<const float4*>(out + Z_OFF) + (size_t)blockIdx.x * 3072;
        #pragma unroll
        for (int m = 0; m < 12; ++m) {
            const int idx = tid + 256 * m;
            const int row = idx / 12, c4 = idx - row * 12;
            *reinterpret_cast<float4*>(&sz[row][c4 * 4]) = zf4[idx];
        }
    }
    __syncthreads();

    const int lane = tid & 63;
    const int wv   = tid >> 6;
    const int rg   = lane >> 3;
    const int cg   = lane & 7;
    const int rowb = wv * 64 + rg;
    const int colb = cg * 8;

    float acc[8][8];
    {
        float bd[8];
        *reinterpret_cast<float4*>(&bd[0]) = *reinterpret_cast<const float4*>(&sbd[colb]);
        *reinterpret_cast<float4*>(&bd[4]) = *reinterpret_cast<const float4*>(&sbd[colb + 4]);
        #pragma unroll
        for (int k = 0; k < 8; ++k)
            #pragma unroll
            for (int c = 0; c < 8; ++c) acc[k][c] = bd[c];
    }

    #pragma unroll 2
    for (int h4 = 0; h4 < 12; ++h4) {
        float4 zf[8];
        #pragma unroll
        for (int k = 0; k < 8; ++k)
            zf[k] = *reinterpret_cast<const float4*>(&sz[rowb + 8 * k][h4 * 4]);
        #pragma unroll
        for (int j = 0; j < 4; ++j) {
            const float4 w0 = *reinterpret_cast<const float4*>(&swT[h4 * 4 + j][colb]);
            const float4 w1 = *reinterpret_cast<const float4*>(&swT[h4 * 4 + j][colb + 4]);
            #pragma unroll
            for (int k = 0; k < 8; ++k) {
                const float zv = j == 0 ? zf[k].x : (j == 1 ? zf[k].y : (j == 2 ? zf[k].z : zf[k].w));
                acc[k][0] = fmaf(zv, w0.x, acc[k][0]);
                acc[k][1] = fmaf(zv, w0.y, acc[k][1]);
                acc[k][2] = fmaf(zv, w0.z, acc[k][2]);
                acc[k][3] = fmaf(zv, w0.w, acc[k][3]);
                acc[k][4] = fmaf(zv, w1.x, acc[k][4]);
                acc[k][5] = fmaf(zv, w1.y, acc[k][5]);
                acc[k][6] = fmaf(zv, w1.z, acc[k][6]);
                acc[k][7] = fmaf(zv, w1.w, acc[k][7]);
            }
        }
    }

    const size_t row0 = (size_t)blockIdx.x * 256 + rowb;
    #pragma unroll
    for (int k = 0; k < 8; ++k) {
        float* dst = out + (row0 + 8 * k) * 64 + colb;
        *reinterpret_cast<float4*>(dst)     = make_float4(acc[k][0], acc[k][1], acc[k][2], acc[k][3]);
        *reinterpret_cast<float4*>(dst + 4) = make_float4(acc[k][4], acc[k][5], acc[k][6], acc[k][7]);
    }
}

extern "C" void kernel_launch(void* const* d_in, const int* in_sizes, int n_in,
                              void* d_out, int out_size, void* d_ws, size_t ws_size,
                              hipStream_t stream) {
    const float* x    = (const float*)d_in[0];
    const float* Wenc = (const float*)d_in[1];
    const float* benc = (const float*)d_in[2];
    const float* Wmem = (const float*)d_in[3];
    const float* bmem = (const float*)d_in[4];
    const float* Wdec = (const float*)d_in[5];
    const float* bdec = (const float*)d_in[6];
    const float* Wcls = (const float*)d_in[7];
    const float* bcls = (const float*)d_in[8];
    float* out = (float*)d_out;

    k_powA<<<dim3(1), dim3(576), 0, stream>>>(Wmem, out);
    k_enc<<<dim3((B_ * T_) / 128), dim3(128), 0, stream>>>(x, Wenc, benc, bmem, out);
    k_p1<<<dim3(NC / CPB), dim3(128), 0, stream>>>(Wmem, out, out + S0_OFF);
    k_p2<<<dim3(B_), dim3(64), 0, stream>>>(out);
    k_p3<<<dim3(NC / CPB), dim3(128), 0, stream>>>(Wmem, out, out + MIN_OFF, out + Z_OFF);
    k_cls<<<dim3(B_), dim3(64), 0, stream>>>(Wcls, bcls, out);
    k_dec<<<dim3((B_ * T_) / 256), dim3(256), 0, stream>>>(Wdec, bdec, out);
}

// Round 15
// 496.091 us; speedup vs baseline: 1.2871x; 1.1815x over previous
//
#include <hip/hip_runtime.h>
#include <cstdint>
#include <cstddef>

#define B_ 512
#define T_ 2048
#define D_ 64
#define H_ 48
#define C_ 3
#define LCH 16           // chunk length
#define KCH 128          // chunks per batch
#define NC  65536        // total chains = B_*KCH
#define CPB 128          // chains per scan block == KCH (block = one batch)

#define RECON_FLOATS ((size_t)B_ * T_ * D_)            // 67,108,864 floats (output 0)
#define LOGIT_FLOATS ((size_t)B_ * C_)                 // 1536 floats      (output 1)
#define Z_OFF        (RECON_FLOATS + LOGIT_FLOATS)     // z region         (output 2)
// u stash (std layout, 50,331,648 floats) at out[0..); dec overwrites it last.
#define A16_OFF  ((size_t)59768832)                    // A^16 row-major (2304 floats)

// ---------------- encoder GEMM (round-8 verbatim) ----------------
__global__ __launch_bounds__(128) void k_enc(
    const float* __restrict__ x, const float* __restrict__ Wenc,
    const float* __restrict__ benc, const float* __restrict__ bmem,
    float* __restrict__ out)
{
    __shared__ float sx[128][68];
    __shared__ float sw[48][68];
    __shared__ float sbe[48];

    const int tid = threadIdx.x;

    {
        const float4* wf4 = reinterpret_cast<const float4*>(Wenc);
        #pragma unroll
        for (int m = 0; m < 6; ++m) {
            const int idx = tid + 128 * m;
            const int c = idx >> 4, d4 = idx & 15;
            *reinterpret_cast<float4*>(&sw[c][d4 * 4]) = wf4[idx];
        }
    }
    if (tid < 48) sbe[tid] = benc[tid] + bmem[tid];

    {
        const float4* xf4 = reinterpret_cast<const float4*>(x) + (size_t)blockIdx.x * 2048;
        #pragma unroll
        for (int m = 0; m < 16; ++m) {
            const int idx = tid + 128 * m;
            const int row = idx >> 4, d4 = idx & 15;
            *reinterpret_cast<float4*>(&sx[row][d4 * 4]) = xf4[idx];
        }
    }
    __syncthreads();

    const int lane = tid & 63;
    const int wv   = tid >> 6;
    const int rg   = lane >> 2;
    const int cg   = lane & 3;
    const int rowb = wv * 64 + rg;
    const int colb = cg * 12;

    float acc[4][12];
    {
        float bia[12];
        #pragma unroll
        for (int m = 0; m < 3; ++m)
            *reinterpret_cast<float4*>(&bia[4 * m]) = *reinterpret_cast<const float4*>(&sbe[colb + 4 * m]);
        #pragma unroll
        for (int k = 0; k < 4; ++k)
            #pragma unroll
            for (int i = 0; i < 12; ++i) acc[k][i] = bia[i];
    }

    #pragma unroll 2
    for (int d4 = 0; d4 < 16; ++d4) {
        float4 xf[4];
        #pragma unroll
        for (int k = 0; k < 4; ++k)
            xf[k] = *reinterpret_cast<const float4*>(&sx[rowb + 16 * k][d4 * 4]);
        #pragma unroll
        for (int i = 0; i < 12; ++i) {
            const float4 wvv = *reinterpret_cast<const float4*>(&sw[colb + i][d4 * 4]);
            #pragma unroll
            for (int k = 0; k < 4; ++k)
                acc[k][i] = fmaf(xf[k].x, wvv.x, fmaf(xf[k].y, wvv.y,
                             fmaf(xf[k].z, wvv.z, fmaf(xf[k].w, wvv.w, acc[k][i]))));
        }
    }

    const size_t row0 = (size_t)blockIdx.x * 128 + rowb;
    #pragma unroll
    for (int k = 0; k < 4; ++k) {
        float* dst = out + (row0 + 16 * k) * 48 + colb;
        #pragma unroll
        for (int m = 0; m < 3; ++m)
            *reinterpret_cast<float4*>(dst + 4 * m) =
                make_float4(acc[k][4 * m], acc[k][4 * m + 1], acc[k][4 * m + 2], acc[k][4 * m + 3]);
    }
}

// ---------------- A^16 via 4 squarings (r14 verbatim) ----------------
__global__ __launch_bounds__(576) void k_powA(
    const float* __restrict__ Wmem, float* __restrict__ out)
{
    __shared__ float a0[48 * 49];
    __shared__ float a1[48 * 49];
    const int tid = threadIdx.x;

    for (int idx = tid; idx < 2304; idx += 576) {
        const int i = idx / 48, j = idx - i * 48;
        a0[i * 49 + j] = 0.1f * Wmem[idx] + (i == j ? 0.9f : 0.0f);
    }
    __syncthreads();

    float* src = a0;
    float* dst = a1;
    #pragma unroll 1
    for (int it = 0; it < 4; ++it) {
        float v[4];
        #pragma unroll
        for (int q = 0; q < 4; ++q) {
            const int o = tid + 576 * q;
            const int i = o / 48, j = o - i * 48;
            float acc = 0.f;
            #pragma unroll
            for (int k = 0; k < 48; ++k)
                acc = fmaf(src[i * 49 + k], src[k * 49 + j], acc);
            v[q] = acc;
        }
        #pragma unroll
        for (int q = 0; q < 4; ++q) {
            const int o = tid + 576 * q;
            const int i = o / 48, j = o - i * 48;
            dst[i * 49 + j] = v[q];
        }
        __syncthreads();
        float* t = src; src = dst; dst = t;
    }
    for (int idx = tid; idx < 2304; idx += 576) {
        const int i = idx / 48, j = idx - i * 48;
        out[A16_OFF + idx] = src[i * 49 + j];
    }
}

// iterated-GEMM machinery (r14-validated): thread tile 6 rows x 8 chains
#define LOAD_UREG(sidx)                                                         \
    {                                                                           \
        const float* pb = u + (c0 + cbase) * 768 + (size_t)(sidx) * 48 + r0;    \
        _Pragma("unroll")                                                       \
        for (int j = 0; j < 8; ++j) {                                           \
            _Pragma("unroll")                                                   \
            for (int e = 0; e < 3; ++e) {                                       \
                const float2 v = *reinterpret_cast<const float2*>(pb + j * 768 + 2 * e); \
                ureg[j][2 * e] = v.x; ureg[j][2 * e + 1] = v.y;                 \
            }                                                                   \
        }                                                                       \
    }

#define GEMM_STEP                                                               \
    float acc[6][8];                                                            \
    _Pragma("unroll")                                                           \
    for (int r = 0; r < 6; ++r)                                                 \
        _Pragma("unroll")                                                       \
        for (int j = 0; j < 8; ++j) acc[r][j] = ureg[j][r];                     \
    LOAD_UREG(s + 1 < LCH ? s + 1 : LCH - 1)                                    \
    _Pragma("unroll 2")                                                         \
    for (int k4 = 0; k4 < 12; ++k4) {                                           \
        float4 av[6];                                                           \
        _Pragma("unroll")                                                       \
        for (int r = 0; r < 6; ++r)                                             \
            av[r] = *reinterpret_cast<const float4*>(&sA[(r0 + r) * 52 + k4 * 4]); \
        float4 mv0[4], mv1[4];                                                  \
        _Pragma("unroll")                                                       \
        for (int kk = 0; kk < 4; ++kk) {                                        \
            mv0[kk] = *reinterpret_cast<const float4*>(&sM[(k4 * 4 + kk) * 132 + cbase]);     \
            mv1[kk] = *reinterpret_cast<const float4*>(&sM[(k4 * 4 + kk) * 132 + cbase + 4]); \
        }                                                                       \
        _Pragma("unroll")                                                       \
        for (int kk = 0; kk < 4; ++kk) {                                        \
            _Pragma("unroll")                                                   \
            for (int r = 0; r < 6; ++r) {                                       \
                const float a = kk == 0 ? av[r].x : kk == 1 ? av[r].y           \
                              : kk == 2 ? av[r].z : av[r].w;                    \
                acc[r][0] = fmaf(a, mv0[kk].x, acc[r][0]);                      \
                acc[r][1] = fmaf(a, mv0[kk].y, acc[r][1]);                      \
                acc[r][2] = fmaf(a, mv0[kk].z, acc[r][2]);                      \
                acc[r][3] = fmaf(a, mv0[kk].w, acc[r][3]);                      \
                acc[r][4] = fmaf(a, mv1[kk].x, acc[r][4]);                      \
                acc[r][5] = fmaf(a, mv1[kk].y, acc[r][5]);                      \
                acc[r][6] = fmaf(a, mv1[kk].z, acc[r][6]);                      \
                acc[r][7] = fmaf(a, mv1[kk].w, acc[r][7]);                      \
            }                                                                   \
        }                                                                       \
    }

#define WRITE_M                                                                 \
    __syncthreads();                                                            \
    _Pragma("unroll")                                                           \
    for (int r = 0; r < 6; ++r) {                                               \
        *reinterpret_cast<float4*>(&sM[(r0 + r) * 132 + cbase]) =               \
            make_float4(acc[r][0], acc[r][1], acc[r][2], acc[r][3]);            \
        *reinterpret_cast<float4*>(&sM[(r0 + r) * 132 + cbase + 4]) =           \
            make_float4(acc[r][4], acc[r][5], acc[r][6], acc[r][7]);            \
    }                                                                           \
    __syncthreads();

// ---------------- fused scan: p1 + p2 + p3 + zsum/logits, one block per batch ----------------
__global__ __launch_bounds__(128) void k_scan(
    const float* __restrict__ Wmem, const float* __restrict__ A16g,
    const float* __restrict__ Wcls, const float* __restrict__ bcls,
    const float* __restrict__ u, float* __restrict__ z, float* __restrict__ logits)
{
    __shared__ float sA[48 * 52];     // A row-major
    __shared__ float sB[48 * 52];     // A^16 row-major
    __shared__ float sM[48 * 132];    // state columns (S0 -> MIN -> running state)
    __shared__ float szs[48];

    const int tid = threadIdx.x;
    const int b   = blockIdx.x;

    for (int idx = tid; idx < 2304; idx += 128) {
        const int i = idx / 48, j = idx - i * 48;
        sA[i * 52 + j] = 0.1f * Wmem[idx] + (i == j ? 0.9f : 0.0f);
        sB[i * 52 + j] = A16g[idx];
    }
    for (int idx = tid; idx < 48 * 132; idx += 128) sM[idx] = 0.f;

    const int rowg  = tid >> 4;          // 0..7
    const int colg  = tid & 15;          // 0..15
    const int r0    = rowg * 6;
    const int cbase = colg * 8;
    const size_t c0 = (size_t)b * CPB;

    float ureg[8][6];
    LOAD_UREG(0)
    __syncthreads();

    // ---- p1: 16 GEMM steps from zero; sM ends as S0 per chunk-column ----
    #pragma unroll 1
    for (int s = 0; s < LCH; ++s) {
        GEMM_STEP
        WRITE_M
    }

    // ---- p2: wave 0 runs the serial boundary combine entirely in LDS ----
    if (tid < 64) {
        const int h = tid < 48 ? tid : 0;
        float w16[48];
        #pragma unroll
        for (int j4 = 0; j4 < 12; ++j4) {
            const float4 w = *reinterpret_cast<const float4*>(&sB[h * 52 + 4 * j4]);
            w16[4 * j4 + 0] = w.x; w16[4 * j4 + 1] = w.y;
            w16[4 * j4 + 2] = w.z; w16[4 * j4 + 3] = w.w;
        }
        float E = 0.f;
        #pragma unroll 1
        for (int k = 0; k < KCH; ++k) {
            const float s0v = (tid < 48) ? sM[h * 132 + k] : 0.f;
            if (tid < 48) sM[h * 132 + k] = E;      // MIN[k] = state entering chunk k
            float a0 = s0v, a1 = 0.f, a2 = 0.f, a3 = 0.f, a4 = 0.f, a5 = 0.f, a6 = 0.f, a7 = 0.f;
            #pragma unroll
            for (int g = 0; g < 6; ++g) {
                const int j = 8 * g;
                const float m0 = __int_as_float(__builtin_amdgcn_readlane(__float_as_int(E), j + 0));
                const float m1 = __int_as_float(__builtin_amdgcn_readlane(__float_as_int(E), j + 1));
                const float m2 = __int_as_float(__builtin_amdgcn_readlane(__float_as_int(E), j + 2));
                const float m3 = __int_as_float(__builtin_amdgcn_readlane(__float_as_int(E), j + 3));
                const float m4 = __int_as_float(__builtin_amdgcn_readlane(__float_as_int(E), j + 4));
                const float m5 = __int_as_float(__builtin_amdgcn_readlane(__float_as_int(E), j + 5));
                const float m6 = __int_as_float(__builtin_amdgcn_readlane(__float_as_int(E), j + 6));
                const float m7 = __int_as_float(__builtin_amdgcn_readlane(__float_as_int(E), j + 7));
                a0 = fmaf(m0, w16[j + 0], a0);
                a1 = fmaf(m1, w16[j + 1], a1);
                a2 = fmaf(m2, w16[j + 2], a2);
                a3 = fmaf(m3, w16[j + 3], a3);
                a4 = fmaf(m4, w16[j + 4], a4);
                a5 = fmaf(m5, w16[j + 5], a5);
                a6 = fmaf(m6, w16[j + 6], a6);
                a7 = fmaf(m7, w16[j + 7], a7);
            }
            E = ((a0 + a1) + (a2 + a3)) + ((a4 + a5) + (a6 + a7));
        }
    }
    __syncthreads();

    // ---- p3: 16 GEMM steps from MIN (already in sM); emit z + row-sum partials ----
    LOAD_UREG(0)
    float zrow[6];
    #pragma unroll
    for (int r = 0; r < 6; ++r) zrow[r] = 0.f;
    const float kExp = -0.14426950408889634f;   // -0.1*log2(e): z = sigmoid(ms/10)

    #pragma unroll 1
    for (int s = 0; s < LCH; ++s) {
        GEMM_STEP
        {
            float* zb = z + (c0 + cbase) * 768 + (size_t)s * 48 + r0;
            #pragma unroll
            for (int j = 0; j < 8; ++j) {
                float zq[6];
                #pragma unroll
                for (int r = 0; r < 6; ++r) {
                    zq[r] = __builtin_amdgcn_rcpf(1.0f + __builtin_amdgcn_exp2f(acc[r][j] * kExp));
                    zrow[r] += zq[r];
                }
                #pragma unroll
                for (int e = 0; e < 3; ++e)
                    *reinterpret_cast<float2*>(zb + j * 768 + 2 * e) = make_float2(zq[2 * e], zq[2 * e + 1]);
            }
        }
        WRITE_M
    }

    // ---- logits: reduce zrow partials over the block, apply Wcls ----
    #pragma unroll
    for (int r = 0; r < 6; ++r)
        sM[(r0 + r) * 132 + colg] = zrow[r];
    __syncthreads();
    if (tid < 48) {
        float a = 0.f;
        #pragma unroll
        for (int c = 0; c < 16; ++c) a += sM[tid * 132 + c];
        szs[tid] = a;
    }
    __syncthreads();
    if (tid < C_) {
        float acc2 = 0.f;
        #pragma unroll
        for (int hh = 0; hh < 48; ++hh) acc2 = fmaf(szs[hh], Wcls[tid * 48 + hh], acc2);
        logits[(size_t)b * C_ + tid] = acc2 * (1.0f / (float)T_) + bcls[tid];
    }
}

// ---------------- decoder GEMM (round-8 verbatim) ----------------
__global__ __launch_bounds__(256) void k_dec(
    const float* __restrict__ Wdec, const float* __restrict__ bdec,
    float* __restrict__ out)
{
    __shared__ float sz[256][52];
    __shared__ float swT[48][68];
    __shared__ float sbd[64];

    const int tid = threadIdx.x;

    #pragma unroll
    for (int m = 0; m < 12; ++m) {
        const int idx = tid + 256 * m;
        const int d = idx / 48, hh = idx - d * 48;
        swT[hh][d] = Wdec[idx];
    }
    if (tid < 64) sbd[tid] = bdec[tid];

    {
        const float4* zf4 = reinterpret_cast<const float4*>(out + Z_OFF) + (size_t)blockIdx.x * 3072;
        #pragma unroll
        for (int m = 0; m < 12; ++m) {
            const int idx = tid + 256 * m;
            const int row = idx / 12, c4 = idx - row * 12;
            *reinterpret_cast<float4*>(&sz[row][c4 * 4]) = zf4[idx];
        }
    }
    __syncthreads();

    const int lane = tid & 63;
    const int wv   = tid >> 6;
    const int rg   = lane >> 3;
    const int cg   = lane & 7;
    const int rowb = wv * 64 + rg;
    const int colb = cg * 8;

    float acc[8][8];
    {
        float bd[8];
        *reinterpret_cast<float4*>(&bd[0]) = *reinterpret_cast<const float4*>(&sbd[colb]);
        *reinterpret_cast<float4*>(&bd[4]) = *reinterpret_cast<const float4*>(&sbd[colb + 4]);
        #pragma unroll
        for (int k = 0; k < 8; ++k)
            #pragma unroll
            for (int c = 0; c < 8; ++c) acc[k][c] = bd[c];
    }

    #pragma unroll 2
    for (int h4 = 0; h4 < 12; ++h4) {
        float4 zf[8];
        #pragma unroll
        for (int k = 0; k < 8; ++k)
            zf[k] = *reinterpret_cast<const float4*>(&sz[rowb + 8 * k][h4 * 4]);
        #pragma unroll
        for (int j = 0; j < 4; ++j) {
            const float4 w0 = *reinterpret_cast<const float4*>(&swT[h4 * 4 + j][colb]);
            const float4 w1 = *reinterpret_cast<const float4*>(&swT[h4 * 4 + j][colb + 4]);
            #pragma unroll
            for (int k = 0; k < 8; ++k) {
                const float zv = j == 0 ? zf[k].x : (j == 1 ? zf[k].y : (j == 2 ? zf[k].z : zf[k].w));
                acc[k][0] = fmaf(zv, w0.x, acc[k][0]);
                acc[k][1] = fmaf(zv, w0.y, acc[k][1]);
                acc[k][2] = fmaf(zv, w0.z, acc[k][2]);
                acc[k][3] = fmaf(zv, w0.w, acc[k][3]);
                acc[k][4] = fmaf(zv, w1.x, acc[k][4]);
                acc[k][5] = fmaf(zv, w1.y, acc[k][5]);
                acc[k][6] = fmaf(zv, w1.z, acc[k][6]);
                acc[k][7] = fmaf(zv, w1.w, acc[k][7]);
            }
        }
    }

    const size_t row0 = (size_t)blockIdx.x * 256 + rowb;
    #pragma unroll
    for (int k = 0; k < 8; ++k) {
        float* dst = out + (row0 + 8 * k) * 64 + colb;
        *reinterpret_cast<float4*>(dst)     = make_float4(acc[k][0], acc[k][1], acc[k][2], acc[k][3]);
        *reinterpret_cast<float4*>(dst + 4) = make_float4(acc[k][4], acc[k][5], acc[k][6], acc[k][7]);
    }
}

extern "C" void kernel_launch(void* const* d_in, const int* in_sizes, int n_in,
                              void* d_out, int out_size, void* d_ws, size_t ws_size,
                              hipStream_t stream) {
    const float* x    = (const float*)d_in[0];
    const float* Wenc = (const float*)d_in[1];
    const float* benc = (const float*)d_in[2];
    const float* Wmem = (const float*)d_in[3];
    const float* bmem = (const float*)d_in[4];
    const float* Wdec = (const float*)d_in[5];
    const float* bdec = (const float*)d_in[6];
    const float* Wcls = (const float*)d_in[7];
    const float* bcls = (const float*)d_in[8];
    float* out = (float*)d_out;

    k_powA<<<dim3(1), dim3(576), 0, stream>>>(Wmem, out);
    k_enc<<<dim3((B_ * T_) / 128), dim3(128), 0, stream>>>(x, Wenc, benc, bmem, out);
    k_scan<<<dim3(B_), dim3(128), 0, stream>>>(Wmem, out + A16_OFF, Wcls, bcls,
                                               out, out + Z_OFF, out + RECON_FLOATS);
    k_dec<<<dim3((B_ * T_) / 256), dim3(256), 0, stream>>>(Wdec, bdec, out);
}

// Round 16
// 488.637 us; speedup vs baseline: 1.3068x; 1.0153x over previous
//
#include <hip/hip_runtime.h>
#include <cstdint>
#include <cstddef>

#define B_ 512
#define T_ 2048
#define D_ 64
#define H_ 48
#define C_ 3
#define LCH 16           // chunk length
#define KCH 128          // chunks per batch
#define NC  65536        // total chains = B_*KCH
#define CPB 128          // chains per scan block == KCH (block = one batch)
#define SMS 162          // sM row stride (floats): 2-way-free banks everywhere

#define RECON_FLOATS ((size_t)B_ * T_ * D_)            // 67,108,864 floats (output 0)
#define LOGIT_FLOATS ((size_t)B_ * C_)                 // 1536 floats      (output 1)
#define Z_OFF        (RECON_FLOATS + LOGIT_FLOATS)     // z region         (output 2)
// u stash (std layout, 50,331,648 floats) at out[0..); dec overwrites it last.
#define A16_OFF  ((size_t)59768832)                    // A^16 row-major (2304 floats)

// ---------------- encoder GEMM (round-8 verbatim) ----------------
__global__ __launch_bounds__(128) void k_enc(
    const float* __restrict__ x, const float* __restrict__ Wenc,
    const float* __restrict__ benc, const float* __restrict__ bmem,
    float* __restrict__ out)
{
    __shared__ float sx[128][68];
    __shared__ float sw[48][68];
    __shared__ float sbe[48];

    const int tid = threadIdx.x;

    {
        const float4* wf4 = reinterpret_cast<const float4*>(Wenc);
        #pragma unroll
        for (int m = 0; m < 6; ++m) {
            const int idx = tid + 128 * m;
            const int c = idx >> 4, d4 = idx & 15;
            *reinterpret_cast<float4*>(&sw[c][d4 * 4]) = wf4[idx];
        }
    }
    if (tid < 48) sbe[tid] = benc[tid] + bmem[tid];

    {
        const float4* xf4 = reinterpret_cast<const float4*>(x) + (size_t)blockIdx.x * 2048;
        #pragma unroll
        for (int m = 0; m < 16; ++m) {
            const int idx = tid + 128 * m;
            const int row = idx >> 4, d4 = idx & 15;
            *reinterpret_cast<float4*>(&sx[row][d4 * 4]) = xf4[idx];
        }
    }
    __syncthreads();

    const int lane = tid & 63;
    const int wv   = tid >> 6;
    const int rg   = lane >> 2;
    const int cg   = lane & 3;
    const int rowb = wv * 64 + rg;
    const int colb = cg * 12;

    float acc[4][12];
    {
        float bia[12];
        #pragma unroll
        for (int m = 0; m < 3; ++m)
            *reinterpret_cast<float4*>(&bia[4 * m]) = *reinterpret_cast<const float4*>(&sbe[colb + 4 * m]);
        #pragma unroll
        for (int k = 0; k < 4; ++k)
            #pragma unroll
            for (int i = 0; i < 12; ++i) acc[k][i] = bia[i];
    }

    #pragma unroll 2
    for (int d4 = 0; d4 < 16; ++d4) {
        float4 xf[4];
        #pragma unroll
        for (int k = 0; k < 4; ++k)
            xf[k] = *reinterpret_cast<const float4*>(&sx[rowb + 16 * k][d4 * 4]);
        #pragma unroll
        for (int i = 0; i < 12; ++i) {
            const float4 wvv = *reinterpret_cast<const float4*>(&sw[colb + i][d4 * 4]);
            #pragma unroll
            for (int k = 0; k < 4; ++k)
                acc[k][i] = fmaf(xf[k].x, wvv.x, fmaf(xf[k].y, wvv.y,
                             fmaf(xf[k].z, wvv.z, fmaf(xf[k].w, wvv.w, acc[k][i]))));
        }
    }

    const size_t row0 = (size_t)blockIdx.x * 128 + rowb;
    #pragma unroll
    for (int k = 0; k < 4; ++k) {
        float* dst = out + (row0 + 16 * k) * 48 + colb;
        #pragma unroll
        for (int m = 0; m < 3; ++m)
            *reinterpret_cast<float4*>(dst + 4 * m) =
                make_float4(acc[k][4 * m], acc[k][4 * m + 1], acc[k][4 * m + 2], acc[k][4 * m + 3]);
    }
}

// ---------------- A^16 via 4 squarings (r14 verbatim) ----------------
__global__ __launch_bounds__(576) void k_powA(
    const float* __restrict__ Wmem, float* __restrict__ out)
{
    __shared__ float a0[48 * 49];
    __shared__ float a1[48 * 49];
    const int tid = threadIdx.x;

    for (int idx = tid; idx < 2304; idx += 576) {
        const int i = idx / 48, j = idx - i * 48;
        a0[i * 49 + j] = 0.1f * Wmem[idx] + (i == j ? 0.9f : 0.0f);
    }
    __syncthreads();

    float* src = a0;
    float* dst = a1;
    #pragma unroll 1
    for (int it = 0; it < 4; ++it) {
        float v[4];
        #pragma unroll
        for (int q = 0; q < 4; ++q) {
            const int o = tid + 576 * q;
            const int i = o / 48, j = o - i * 48;
            float acc = 0.f;
            #pragma unroll
            for (int k = 0; k < 48; ++k)
                acc = fmaf(src[i * 49 + k], src[k * 49 + j], acc);
            v[q] = acc;
        }
        #pragma unroll
        for (int q = 0; q < 4; ++q) {
            const int o = tid + 576 * q;
            const int i = o / 48, j = o - i * 48;
            dst[i * 49 + j] = v[q];
        }
        __syncthreads();
        float* t = src; src = dst; dst = t;
    }
    for (int idx = tid; idx < 2304; idx += 576) {
        const int i = idx / 48, j = idx - i * 48;
        out[A16_OFF + idx] = src[i * 49 + j];
    }
}

// iterated-GEMM machinery: thread tile 6 rows x 8 chains; swizzled sM
#define LOAD_UREG(sidx)                                                         \
    {                                                                           \
        const float* pb = u + (c0 + cbase) * 768 + (size_t)(sidx) * 48 + r0;    \
        _Pragma("unroll")                                                       \
        for (int j = 0; j < 8; ++j) {                                           \
            _Pragma("unroll")                                                   \
            for (int e = 0; e < 3; ++e) {                                       \
                const float2 v = *reinterpret_cast<const float2*>(pb + j * 768 + 2 * e); \
                ureg[j][2 * e] = v.x; ureg[j][2 * e + 1] = v.y;                 \
            }                                                                   \
        }                                                                       \
    }

#define GEMM_STEP                                                               \
    float acc[6][8];                                                            \
    _Pragma("unroll")                                                           \
    for (int r = 0; r < 6; ++r)                                                 \
        _Pragma("unroll")                                                       \
        for (int j = 0; j < 8; ++j) acc[r][j] = ureg[j][r];                     \
    LOAD_UREG(s + 1 < LCH ? s + 1 : LCH - 1)                                    \
    _Pragma("unroll")                                                           \
    for (int k4 = 0; k4 < 12; ++k4) {                                           \
        float4 av[6];                                                           \
        _Pragma("unroll")                                                       \
        for (int r = 0; r < 6; ++r)                                             \
            av[r] = *reinterpret_cast<const float4*>(&sA[(r0 + r) * 52 + k4 * 4]); \
        float4 mv0[4], mv1[4];                                                  \
        _Pragma("unroll")                                                       \
        for (int kk = 0; kk < 4; ++kk) {                                        \
            mv0[kk] = *reinterpret_cast<const float4*>(&sM[(k4 * 4 + kk) * SMS + pcb]);     \
            mv1[kk] = *reinterpret_cast<const float4*>(&sM[(k4 * 4 + kk) * SMS + pcb + 4]); \
        }                                                                       \
        _Pragma("unroll")                                                       \
        for (int kk = 0; kk < 4; ++kk) {                                        \
            _Pragma("unroll")                                                   \
            for (int r = 0; r < 6; ++r) {                                       \
                const float a = kk == 0 ? av[r].x : kk == 1 ? av[r].y           \
                              : kk == 2 ? av[r].z : av[r].w;                    \
                acc[r][0] = fmaf(a, mv0[kk].x, acc[r][0]);                      \
                acc[r][1] = fmaf(a, mv0[kk].y, acc[r][1]);                      \
                acc[r][2] = fmaf(a, mv0[kk].z, acc[r][2]);                      \
                acc[r][3] = fmaf(a, mv0[kk].w, acc[r][3]);                      \
                acc[r][4] = fmaf(a, mv1[kk].x, acc[r][4]);                      \
                acc[r][5] = fmaf(a, mv1[kk].y, acc[r][5]);                      \
                acc[r][6] = fmaf(a, mv1[kk].z, acc[r][6]);                      \
                acc[r][7] = fmaf(a, mv1[kk].w, acc[r][7]);                      \
            }                                                                   \
        }                                                                       \
    }

#define WRITE_M                                                                 \
    __syncthreads();                                                            \
    _Pragma("unroll")                                                           \
    for (int r = 0; r < 6; ++r) {                                               \
        *reinterpret_cast<float4*>(&sM[(r0 + r) * SMS + pcb]) =                 \
            make_float4(acc[r][0], acc[r][1], acc[r][2], acc[r][3]);            \
        *reinterpret_cast<float4*>(&sM[(r0 + r) * SMS + pcb + 4]) =             \
            make_float4(acc[r][4], acc[r][5], acc[r][6], acc[r][7]);            \
    }                                                                           \
    __syncthreads();

// ---------------- fused scan: p1 + p2 + p3 + zsum/logits, one block per batch ----------------
__global__ __launch_bounds__(128) void k_scan(
    const float* __restrict__ Wmem, const float* __restrict__ A16g,
    const float* __restrict__ Wcls, const float* __restrict__ bcls,
    const float* __restrict__ u, float* __restrict__ z, float* __restrict__ logits)
{
    __shared__ float sA[48 * 52];     // A row-major
    __shared__ float sB[48 * 52];     // A^16 row-major
    __shared__ float sM[48 * SMS];    // state columns, swizzled (group g at g*10)
    __shared__ float szs[48];

    const int tid = threadIdx.x;
    const int b   = blockIdx.x;

    for (int idx = tid; idx < 2304; idx += 128) {
        const int i = idx / 48, j = idx - i * 48;
        sA[i * 52 + j] = 0.1f * Wmem[idx] + (i == j ? 0.9f : 0.0f);
        sB[i * 52 + j] = A16g[idx];
    }
    for (int idx = tid; idx < 48 * SMS; idx += 128) sM[idx] = 0.f;

    const int rowg  = tid >> 4;          // 0..7
    const int colg  = tid & 15;          // 0..15
    const int r0    = rowg * 6;
    const int cbase = colg * 8;          // logical chain base
    const int pcb   = colg * 10;         // physical (swizzled) column base
    const size_t c0 = (size_t)b * CPB;

    float ureg[8][6];
    LOAD_UREG(0)
    __syncthreads();

    // ---- p1: 16 GEMM steps from zero; sM ends as S0 per chunk-column ----
    #pragma unroll 1
    for (int s = 0; s < LCH; ++s) {
        GEMM_STEP
        WRITE_M
    }

    // ---- p2: wave 0 runs the serial boundary combine entirely in LDS ----
    if (tid < 64) {
        const int h = tid < 48 ? tid : 0;
        float w16[48];
        #pragma unroll
        for (int j4 = 0; j4 < 12; ++j4) {
            const float4 w = *reinterpret_cast<const float4*>(&sB[h * 52 + 4 * j4]);
            w16[4 * j4 + 0] = w.x; w16[4 * j4 + 1] = w.y;
            w16[4 * j4 + 2] = w.z; w16[4 * j4 + 3] = w.w;
        }
        float E = 0.f;
        #pragma unroll 1
        for (int k = 0; k < KCH; ++k) {
            const int pck = (k >> 3) * 10 + (k & 7);     // swizzled column of chunk k
            const float s0v = (tid < 48) ? sM[h * SMS + pck] : 0.f;
            if (tid < 48) sM[h * SMS + pck] = E;          // MIN[k] = state entering chunk k
            float a0 = s0v, a1 = 0.f, a2 = 0.f, a3 = 0.f, a4 = 0.f, a5 = 0.f, a6 = 0.f, a7 = 0.f;
            #pragma unroll
            for (int g = 0; g < 6; ++g) {
                const int j = 8 * g;
                const float m0 = __int_as_float(__builtin_amdgcn_readlane(__float_as_int(E), j + 0));
                const float m1 = __int_as_float(__builtin_amdgcn_readlane(__float_as_int(E), j + 1));
                const float m2 = __int_as_float(__builtin_amdgcn_readlane(__float_as_int(E), j + 2));
                const float m3 = __int_as_float(__builtin_amdgcn_readlane(__float_as_int(E), j + 3));
                const float m4 = __int_as_float(__builtin_amdgcn_readlane(__float_as_int(E), j + 4));
                const float m5 = __int_as_float(__builtin_amdgcn_readlane(__float_as_int(E), j + 5));
                const float m6 = __int_as_float(__builtin_amdgcn_readlane(__float_as_int(E), j + 6));
                const float m7 = __int_as_float(__builtin_amdgcn_readlane(__float_as_int(E), j + 7));
                a0 = fmaf(m0, w16[j + 0], a0);
                a1 = fmaf(m1, w16[j + 1], a1);
                a2 = fmaf(m2, w16[j + 2], a2);
                a3 = fmaf(m3, w16[j + 3], a3);
                a4 = fmaf(m4, w16[j + 4], a4);
                a5 = fmaf(m5, w16[j + 5], a5);
                a6 = fmaf(m6, w16[j + 6], a6);
                a7 = fmaf(m7, w16[j + 7], a7);
            }
            E = ((a0 + a1) + (a2 + a3)) + ((a4 + a5) + (a6 + a7));
        }
    }
    __syncthreads();

    // ---- p3: 16 GEMM steps from MIN (already in sM); emit z + row-sum partials ----
    LOAD_UREG(0)
    float zrow[6];
    #pragma unroll
    for (int r = 0; r < 6; ++r) zrow[r] = 0.f;
    const float kExp = -0.14426950408889634f;   // -0.1*log2(e): z = sigmoid(ms/10)

    #pragma unroll 1
    for (int s = 0; s < LCH; ++s) {
        GEMM_STEP
        {
            float* zb = z + (c0 + cbase) * 768 + (size_t)s * 48 + r0;
            #pragma unroll
            for (int j = 0; j < 8; ++j) {
                float zq[6];
                #pragma unroll
                for (int r = 0; r < 6; ++r) {
                    zq[r] = __builtin_amdgcn_rcpf(1.0f + __builtin_amdgcn_exp2f(acc[r][j] * kExp));
                    zrow[r] += zq[r];
                }
                #pragma unroll
                for (int e = 0; e < 3; ++e)
                    *reinterpret_cast<float2*>(zb + j * 768 + 2 * e) = make_float2(zq[2 * e], zq[2 * e + 1]);
            }
        }
        if (s + 1 < LCH) { WRITE_M }   // final state write is dead — skip it
    }
    __syncthreads();   // all mv reads of the last step done before sM reuse

    // ---- logits: reduce zrow partials over the block, apply Wcls ----
    #pragma unroll
    for (int r = 0; r < 6; ++r)
        sM[(r0 + r) * SMS + colg] = zrow[r];
    __syncthreads();
    if (tid < 48) {
        float a = 0.f;
        #pragma unroll
        for (int c = 0; c < 16; ++c) a += sM[tid * SMS + c];
        szs[tid] = a;
    }
    __syncthreads();
    if (tid < C_) {
        float acc2 = 0.f;
        #pragma unroll
        for (int hh = 0; hh < 48; ++hh) acc2 = fmaf(szs[hh], Wcls[tid * 48 + hh], acc2);
        logits[(size_t)b * C_ + tid] = acc2 * (1.0f / (float)T_) + bcls[tid];
    }
}

// ---------------- decoder GEMM (round-8 verbatim) ----------------
__global__ __launch_bounds__(256) void k_dec(
    const float* __restrict__ Wdec, const float* __restrict__ bdec,
    float* __restrict__ out)
{
    __shared__ float sz[256][52];
    __shared__ float swT[48][68];
    __shared__ float sbd[64];

    const int tid = threadIdx.x;

    #pragma unroll
    for (int m = 0; m < 12; ++m) {
        const int idx = tid + 256 * m;
        const int d = idx / 48, hh = idx - d * 48;
        swT[hh][d] = Wdec[idx];
    }
    if (tid < 64) sbd[tid] = bdec[tid];

    {
        const float4* zf4 = reinterpret_cast<const float4*>(out + Z_OFF) + (size_t)blockIdx.x * 3072;
        #pragma unroll
        for (int m = 0; m < 12; ++m) {
            const int idx = tid + 256 * m;
            const int row = idx / 12, c4 = idx - row * 12;
            *reinterpret_cast<float4*>(&sz[row][c4 * 4]) = zf4[idx];
        }
    }
    __syncthreads();

    const int lane = tid & 63;
    const int wv   = tid >> 6;
    const int rg   = lane >> 3;
    const int cg   = lane & 7;
    const int rowb = wv * 64 + rg;
    const int colb = cg * 8;

    float acc[8][8];
    {
        float bd[8];
        *reinterpret_cast<float4*>(&bd[0]) = *reinterpret_cast<const float4*>(&sbd[colb]);
        *reinterpret_cast<float4*>(&bd[4]) = *reinterpret_cast<const float4*>(&sbd[colb + 4]);
        #pragma unroll
        for (int k = 0; k < 8; ++k)
            #pragma unroll
            for (int c = 0; c < 8; ++c) acc[k][c] = bd[c];
    }

    #pragma unroll 2
    for (int h4 = 0; h4 < 12; ++h4) {
        float4 zf[8];
        #pragma unroll
        for (int k = 0; k < 8; ++k)
            zf[k] = *reinterpret_cast<const float4*>(&sz[rowb + 8 * k][h4 * 4]);
        #pragma unroll
        for (int j = 0; j < 4; ++j) {
            const float4 w0 = *reinterpret_cast<const float4*>(&swT[h4 * 4 + j][colb]);
            const float4 w1 = *reinterpret_cast<const float4*>(&swT[h4 * 4 + j][colb + 4]);
            #pragma unroll
            for (int k = 0; k < 8; ++k) {
                const float zv = j == 0 ? zf[k].x : (j == 1 ? zf[k].y : (j == 2 ? zf[k].z : zf[k].w));
                acc[k][0] = fmaf(zv, w0.x, acc[k][0]);
                acc[k][1] = fmaf(zv, w0.y, acc[k][1]);
                acc[k][2] = fmaf(zv, w0.z, acc[k][2]);
                acc[k][3] = fmaf(zv, w0.w, acc[k][3]);
                acc[k][4] = fmaf(zv, w1.x, acc[k][4]);
                acc[k][5] = fmaf(zv, w1.y, acc[k][5]);
                acc[k][6] = fmaf(zv, w1.z, acc[k][6]);
                acc[k][7] = fmaf(zv, w1.w, acc[k][7]);
            }
        }
    }

    const size_t row0 = (size_t)blockIdx.x * 256 + rowb;
    #pragma unroll
    for (int k = 0; k < 8; ++k) {
        float* dst = out + (row0 + 8 * k) * 64 + colb;
        *reinterpret_cast<float4*>(dst)     = make_float4(acc[k][0], acc[k][1], acc[k][2], acc[k][3]);
        *reinterpret_cast<float4*>(dst + 4) = make_float4(acc[k][4], acc[k][5], acc[k][6], acc[k][7]);
    }
}

extern "C" void kernel_launch(void* const* d_in, const int* in_sizes, int n_in,
                              void* d_out, int out_size, void* d_ws, size_t ws_size,
                              hipStream_t stream) {
    const float* x    = (const float*)d_in[0];
    const float* Wenc = (const float*)d_in[1];
    const float* benc = (const float*)d_in[2];
    const float* Wmem = (const float*)d_in[3];
    const float* bmem = (const float*)d_in[4];
    const float* Wdec = (const float*)d_in[5];
    const float* bdec = (const float*)d_in[6];
    const float* Wcls = (const float*)d_in[7];
    const float* bcls = (const float*)d_in[8];
    float* out = (float*)d_out;

    k_powA<<<dim3(1), dim3(576), 0, stream>>>(Wmem, out);
    k_enc<<<dim3((B_ * T_) / 128), dim3(128), 0, stream>>>(x, Wenc, benc, bmem, out);
    k_scan<<<dim3(B_), dim3(128), 0, stream>>>(Wmem, out + A16_OFF, Wcls, bcls,
                                               out, out + Z_OFF, out + RECON_FLOATS);
    k_dec<<<dim3((B_ * T_) / 256), dim3(256), 0, stream>>>(Wdec, bdec, out);
}

// Round 17
// 480.756 us; speedup vs baseline: 1.3282x; 1.0164x over previous
//
#include <hip/hip_runtime.h>
#include <cstdint>
#include <cstddef>

#define B_ 512
#define T_ 2048
#define D_ 64
#define H_ 48
#define C_ 3
#define LCH 16           // chunk length
#define KCH 128          // chunks per batch
#define NC  65536        // total chains = B_*KCH
#define CPB 128          // chains per scan block == KCH (block = one batch)
#define SMS 162          // sM row stride (floats): 2-way-free banks everywhere

#define RECON_FLOATS ((size_t)B_ * T_ * D_)            // 67,108,864 floats (output 0)
#define LOGIT_FLOATS ((size_t)B_ * C_)                 // 1536 floats      (output 1)
#define Z_OFF        (RECON_FLOATS + LOGIT_FLOATS)     // z region         (output 2)
// u stash (std layout, 50,331,648 floats) at out[0..); dec overwrites it last.
#define A16_OFF  ((size_t)59768832)                    // A^16 row-major (2304 floats)

// ---------------- encoder GEMM (round-8 verbatim) ----------------
__global__ __launch_bounds__(128) void k_enc(
    const float* __restrict__ x, const float* __restrict__ Wenc,
    const float* __restrict__ benc, const float* __restrict__ bmem,
    float* __restrict__ out)
{
    __shared__ float sx[128][68];
    __shared__ float sw[48][68];
    __shared__ float sbe[48];

    const int tid = threadIdx.x;

    {
        const float4* wf4 = reinterpret_cast<const float4*>(Wenc);
        #pragma unroll
        for (int m = 0; m < 6; ++m) {
            const int idx = tid + 128 * m;
            const int c = idx >> 4, d4 = idx & 15;
            *reinterpret_cast<float4*>(&sw[c][d4 * 4]) = wf4[idx];
        }
    }
    if (tid < 48) sbe[tid] = benc[tid] + bmem[tid];

    {
        const float4* xf4 = reinterpret_cast<const float4*>(x) + (size_t)blockIdx.x * 2048;
        #pragma unroll
        for (int m = 0; m < 16; ++m) {
            const int idx = tid + 128 * m;
            const int row = idx >> 4, d4 = idx & 15;
            *reinterpret_cast<float4*>(&sx[row][d4 * 4]) = xf4[idx];
        }
    }
    __syncthreads();

    const int lane = tid & 63;
    const int wv   = tid >> 6;
    const int rg   = lane >> 2;
    const int cg   = lane & 3;
    const int rowb = wv * 64 + rg;
    const int colb = cg * 12;

    float acc[4][12];
    {
        float bia[12];
        #pragma unroll
        for (int m = 0; m < 3; ++m)
            *reinterpret_cast<float4*>(&bia[4 * m]) = *reinterpret_cast<const float4*>(&sbe[colb + 4 * m]);
        #pragma unroll
        for (int k = 0; k < 4; ++k)
            #pragma unroll
            for (int i = 0; i < 12; ++i) acc[k][i] = bia[i];
    }

    #pragma unroll 2
    for (int d4 = 0; d4 < 16; ++d4) {
        float4 xf[4];
        #pragma unroll
        for (int k = 0; k < 4; ++k)
            xf[k] = *reinterpret_cast<const float4*>(&sx[rowb + 16 * k][d4 * 4]);
        #pragma unroll
        for (int i = 0; i < 12; ++i) {
            const float4 wvv = *reinterpret_cast<const float4*>(&sw[colb + i][d4 * 4]);
            #pragma unroll
            for (int k = 0; k < 4; ++k)
                acc[k][i] = fmaf(xf[k].x, wvv.x, fmaf(xf[k].y, wvv.y,
                             fmaf(xf[k].z, wvv.z, fmaf(xf[k].w, wvv.w, acc[k][i]))));
        }
    }

    const size_t row0 = (size_t)blockIdx.x * 128 + rowb;
    #pragma unroll
    for (int k = 0; k < 4; ++k) {
        float* dst = out + (row0 + 16 * k) * 48 + colb;
        #pragma unroll
        for (int m = 0; m < 3; ++m)
            *reinterpret_cast<float4*>(dst + 4 * m) =
                make_float4(acc[k][4 * m], acc[k][4 * m + 1], acc[k][4 * m + 2], acc[k][4 * m + 3]);
    }
}

// ---------------- A^16 via 4 squarings (r14 verbatim) ----------------
__global__ __launch_bounds__(576) void k_powA(
    const float* __restrict__ Wmem, float* __restrict__ out)
{
    __shared__ float a0[48 * 49];
    __shared__ float a1[48 * 49];
    const int tid = threadIdx.x;

    for (int idx = tid; idx < 2304; idx += 576) {
        const int i = idx / 48, j = idx - i * 48;
        a0[i * 49 + j] = 0.1f * Wmem[idx] + (i == j ? 0.9f : 0.0f);
    }
    __syncthreads();

    float* src = a0;
    float* dst = a1;
    #pragma unroll 1
    for (int it = 0; it < 4; ++it) {
        float v[4];
        #pragma unroll
        for (int q = 0; q < 4; ++q) {
            const int o = tid + 576 * q;
            const int i = o / 48, j = o - i * 48;
            float acc = 0.f;
            #pragma unroll
            for (int k = 0; k < 48; ++k)
                acc = fmaf(src[i * 49 + k], src[k * 49 + j], acc);
            v[q] = acc;
        }
        #pragma unroll
        for (int q = 0; q < 4; ++q) {
            const int o = tid + 576 * q;
            const int i = o / 48, j = o - i * 48;
            dst[i * 49 + j] = v[q];
        }
        __syncthreads();
        float* t = src; src = dst; dst = t;
    }
    for (int idx = tid; idx < 2304; idx += 576) {
        const int i = idx / 48, j = idx - i * 48;
        out[A16_OFF + idx] = src[i * 49 + j];
    }
}

// iterated-GEMM machinery: thread tile 3 rows x 8 chains; 256 threads; swizzled sM
#define LOAD_UREG(sidx)                                                         \
    {                                                                           \
        const float* pb = u + (c0 + cbase) * 768 + (size_t)(sidx) * 48 + r0;    \
        _Pragma("unroll")                                                       \
        for (int j = 0; j < 8; ++j) {                                           \
            ureg[j][0] = pb[j * 768 + 0];                                       \
            ureg[j][1] = pb[j * 768 + 1];                                       \
            ureg[j][2] = pb[j * 768 + 2];                                       \
        }                                                                       \
    }

#define GEMM_STEP                                                               \
    float acc[3][8];                                                            \
    _Pragma("unroll")                                                           \
    for (int r = 0; r < 3; ++r)                                                 \
        _Pragma("unroll")                                                       \
        for (int j = 0; j < 8; ++j) acc[r][j] = ureg[j][r];                     \
    LOAD_UREG(s + 1 < LCH ? s + 1 : LCH - 1)                                    \
    _Pragma("unroll")                                                           \
    for (int k4 = 0; k4 < 12; ++k4) {                                           \
        float4 av[3];                                                           \
        _Pragma("unroll")                                                       \
        for (int r = 0; r < 3; ++r)                                             \
            av[r] = *reinterpret_cast<const float4*>(&sA[(r0 + r) * 52 + k4 * 4]); \
        float4 mv0[4], mv1[4];                                                  \
        _Pragma("unroll")                                                       \
        for (int kk = 0; kk < 4; ++kk) {                                        \
            mv0[kk] = *reinterpret_cast<const float4*>(&sM[(k4 * 4 + kk) * SMS + pcb]);     \
            mv1[kk] = *reinterpret_cast<const float4*>(&sM[(k4 * 4 + kk) * SMS + pcb + 4]); \
        }                                                                       \
        _Pragma("unroll")                                                       \
        for (int kk = 0; kk < 4; ++kk) {                                        \
            _Pragma("unroll")                                                   \
            for (int r = 0; r < 3; ++r) {                                       \
                const float a = kk == 0 ? av[r].x : kk == 1 ? av[r].y           \
                              : kk == 2 ? av[r].z : av[r].w;                    \
                acc[r][0] = fmaf(a, mv0[kk].x, acc[r][0]);                      \
                acc[r][1] = fmaf(a, mv0[kk].y, acc[r][1]);                      \
                acc[r][2] = fmaf(a, mv0[kk].z, acc[r][2]);                      \
                acc[r][3] = fmaf(a, mv0[kk].w, acc[r][3]);                      \
                acc[r][4] = fmaf(a, mv1[kk].x, acc[r][4]);                      \
                acc[r][5] = fmaf(a, mv1[kk].y, acc[r][5]);                      \
                acc[r][6] = fmaf(a, mv1[kk].z, acc[r][6]);                      \
                acc[r][7] = fmaf(a, mv1[kk].w, acc[r][7]);                      \
            }                                                                   \
        }                                                                       \
    }

#define WRITE_M                                                                 \
    __syncthreads();                                                            \
    _Pragma("unroll")                                                           \
    for (int r = 0; r < 3; ++r) {                                               \
        *reinterpret_cast<float4*>(&sM[(r0 + r) * SMS + pcb]) =                 \
            make_float4(acc[r][0], acc[r][1], acc[r][2], acc[r][3]);            \
        *reinterpret_cast<float4*>(&sM[(r0 + r) * SMS + pcb + 4]) =             \
            make_float4(acc[r][4], acc[r][5], acc[r][6], acc[r][7]);            \
    }                                                                           \
    __syncthreads();

// ---------------- fused scan: p1 + p2 + p3 + zsum/logits; 256 threads, one block per batch ----------------
__global__ __launch_bounds__(256) void k_scan(
    const float* __restrict__ Wmem, const float* __restrict__ A16g,
    const float* __restrict__ Wcls, const float* __restrict__ bcls,
    const float* __restrict__ u, float* __restrict__ z, float* __restrict__ logits)
{
    __shared__ float sA[48 * 52];     // A row-major
    __shared__ float sB[48 * 52];     // A^16 row-major
    __shared__ float sM[48 * SMS];    // state columns, swizzled (group g at g*10)
    __shared__ float szs[48];

    const int tid = threadIdx.x;
    const int b   = blockIdx.x;

    for (int idx = tid; idx < 2304; idx += 256) {
        const int i = idx / 48, j = idx - i * 48;
        sA[i * 52 + j] = 0.1f * Wmem[idx] + (i == j ? 0.9f : 0.0f);
        sB[i * 52 + j] = A16g[idx];
    }
    for (int idx = tid; idx < 48 * SMS; idx += 256) sM[idx] = 0.f;

    const int rowg  = tid >> 4;          // 0..15
    const int colg  = tid & 15;          // 0..15
    const int r0    = rowg * 3;          // 3 rows per thread
    const int cbase = colg * 8;          // logical chain base
    const int pcb   = colg * 10;         // physical (swizzled) column base
    const size_t c0 = (size_t)b * CPB;

    float ureg[8][3];
    LOAD_UREG(0)
    __syncthreads();

    // ---- p1: 16 GEMM steps from zero; sM ends as S0 per chunk-column ----
    #pragma unroll 1
    for (int s = 0; s < LCH; ++s) {
        GEMM_STEP
        WRITE_M
    }

    // ---- p2: wave 0 runs the serial boundary combine entirely in LDS ----
    if (tid < 64) {
        const int h = tid < 48 ? tid : 0;
        float w16[48];
        #pragma unroll
        for (int j4 = 0; j4 < 12; ++j4) {
            const float4 w = *reinterpret_cast<const float4*>(&sB[h * 52 + 4 * j4]);
            w16[4 * j4 + 0] = w.x; w16[4 * j4 + 1] = w.y;
            w16[4 * j4 + 2] = w.z; w16[4 * j4 + 3] = w.w;
        }
        float E = 0.f;
        #pragma unroll 1
        for (int k = 0; k < KCH; ++k) {
            const int pck = (k >> 3) * 10 + (k & 7);     // swizzled column of chunk k
            const float s0v = (tid < 48) ? sM[h * SMS + pck] : 0.f;
            if (tid < 48) sM[h * SMS + pck] = E;          // MIN[k] = state entering chunk k
            float a0 = s0v, a1 = 0.f, a2 = 0.f, a3 = 0.f, a4 = 0.f, a5 = 0.f, a6 = 0.f, a7 = 0.f;
            #pragma unroll
            for (int g = 0; g < 6; ++g) {
                const int j = 8 * g;
                const float m0 = __int_as_float(__builtin_amdgcn_readlane(__float_as_int(E), j + 0));
                const float m1 = __int_as_float(__builtin_amdgcn_readlane(__float_as_int(E), j + 1));
                const float m2 = __int_as_float(__builtin_amdgcn_readlane(__float_as_int(E), j + 2));
                const float m3 = __int_as_float(__builtin_amdgcn_readlane(__float_as_int(E), j + 3));
                const float m4 = __int_as_float(__builtin_amdgcn_readlane(__float_as_int(E), j + 4));
                const float m5 = __int_as_float(__builtin_amdgcn_readlane(__float_as_int(E), j + 5));
                const float m6 = __int_as_float(__builtin_amdgcn_readlane(__float_as_int(E), j + 6));
                const float m7 = __int_as_float(__builtin_amdgcn_readlane(__float_as_int(E), j + 7));
                a0 = fmaf(m0, w16[j + 0], a0);
                a1 = fmaf(m1, w16[j + 1], a1);
                a2 = fmaf(m2, w16[j + 2], a2);
                a3 = fmaf(m3, w16[j + 3], a3);
                a4 = fmaf(m4, w16[j + 4], a4);
                a5 = fmaf(m5, w16[j + 5], a5);
                a6 = fmaf(m6, w16[j + 6], a6);
                a7 = fmaf(m7, w16[j + 7], a7);
            }
            E = ((a0 + a1) + (a2 + a3)) + ((a4 + a5) + (a6 + a7));
        }
    }
    __syncthreads();

    // ---- p3: 16 GEMM steps from MIN (already in sM); emit z + row-sum partials ----
    LOAD_UREG(0)
    float zrow[3];
    #pragma unroll
    for (int r = 0; r < 3; ++r) zrow[r] = 0.f;
    const float kExp = -0.14426950408889634f;   // -0.1*log2(e): z = sigmoid(ms/10)

    #pragma unroll 1
    for (int s = 0; s < LCH; ++s) {
        GEMM_STEP
        {
            float* zb = z + (c0 + cbase) * 768 + (size_t)s * 48 + r0;
            #pragma unroll
            for (int j = 0; j < 8; ++j) {
                #pragma unroll
                for (int r = 0; r < 3; ++r) {
                    const float zq = __builtin_amdgcn_rcpf(1.0f + __builtin_amdgcn_exp2f(acc[r][j] * kExp));
                    zrow[r] += zq;
                    zb[j * 768 + r] = zq;
                }
            }
        }
        if (s + 1 < LCH) { WRITE_M }   // final state write is dead — skip it
    }
    __syncthreads();   // all mv reads of the last step done before sM reuse

    // ---- logits: reduce zrow partials over the block, apply Wcls ----
    #pragma unroll
    for (int r = 0; r < 3; ++r)
        sM[(r0 + r) * SMS + colg] = zrow[r];
    __syncthreads();
    if (tid < 48) {
        float a = 0.f;
        #pragma unroll
        for (int c = 0; c < 16; ++c) a += sM[tid * SMS + c];
        szs[tid] = a;
    }
    __syncthreads();
    if (tid < C_) {
        float acc2 = 0.f;
        #pragma unroll
        for (int hh = 0; hh < 48; ++hh) acc2 = fmaf(szs[hh], Wcls[tid * 48 + hh], acc2);
        logits[(size_t)b * C_ + tid] = acc2 * (1.0f / (float)T_) + bcls[tid];
    }
}

// ---------------- decoder GEMM (round-8 verbatim) ----------------
__global__ __launch_bounds__(256) void k_dec(
    const float* __restrict__ Wdec, const float* __restrict__ bdec,
    float* __restrict__ out)
{
    __shared__ float sz[256][52];
    __shared__ float swT[48][68];
    __shared__ float sbd[64];

    const int tid = threadIdx.x;

    #pragma unroll
    for (int m = 0; m < 12; ++m) {
        const int idx = tid + 256 * m;
        const int d = idx / 48, hh = idx - d * 48;
        swT[hh][d] = Wdec[idx];
    }
    if (tid < 64) sbd[tid] = bdec[tid];

    {
        const float4* zf4 = reinterpret_cast<const float4*>(out + Z_OFF) + (size_t)blockIdx.x * 3072;
        #pragma unroll
        for (int m = 0; m < 12; ++m) {
            const int idx = tid + 256 * m;
            const int row = idx / 12, c4 = idx - row * 12;
            *reinterpret_cast<float4*>(&sz[row][c4 * 4]) = zf4[idx];
        }
    }
    __syncthreads();

    const int lane = tid & 63;
    const int wv   = tid >> 6;
    const int rg   = lane >> 3;
    const int cg   = lane & 7;
    const int rowb = wv * 64 + rg;
    const int colb = cg * 8;

    float acc[8][8];
    {
        float bd[8];
        *reinterpret_cast<float4*>(&bd[0]) = *reinterpret_cast<const float4*>(&sbd[colb]);
        *reinterpret_cast<float4*>(&bd[4]) = *reinterpret_cast<const float4*>(&sbd[colb + 4]);
        #pragma unroll
        for (int k = 0; k < 8; ++k)
            #pragma unroll
            for (int c = 0; c < 8; ++c) acc[k][c] = bd[c];
    }

    #pragma unroll 2
    for (int h4 = 0; h4 < 12; ++h4) {
        float4 zf[8];
        #pragma unroll
        for (int k = 0; k < 8; ++k)
            zf[k] = *reinterpret_cast<const float4*>(&sz[rowb + 8 * k][h4 * 4]);
        #pragma unroll
        for (int j = 0; j < 4; ++j) {
            const float4 w0 = *reinterpret_cast<const float4*>(&swT[h4 * 4 + j][colb]);
            const float4 w1 = *reinterpret_cast<const float4*>(&swT[h4 * 4 + j][colb + 4]);
            #pragma unroll
            for (int k = 0; k < 8; ++k) {
                const float zv = j == 0 ? zf[k].x : (j == 1 ? zf[k].y : (j == 2 ? zf[k].z : zf[k].w));
                acc[k][0] = fmaf(zv, w0.x, acc[k][0]);
                acc[k][1] = fmaf(zv, w0.y, acc[k][1]);
                acc[k][2] = fmaf(zv, w0.z, acc[k][2]);
                acc[k][3] = fmaf(zv, w0.w, acc[k][3]);
                acc[k][4] = fmaf(zv, w1.x, acc[k][4]);
                acc[k][5] = fmaf(zv, w1.y, acc[k][5]);
                acc[k][6] = fmaf(zv, w1.z, acc[k][6]);
                acc[k][7] = fmaf(zv, w1.w, acc[k][7]);
            }
        }
    }

    const size_t row0 = (size_t)blockIdx.x * 256 + rowb;
    #pragma unroll
    for (int k = 0; k < 8; ++k) {
        float* dst = out + (row0 + 8 * k) * 64 + colb;
        *reinterpret_cast<float4*>(dst)     = make_float4(acc[k][0], acc[k][1], acc[k][2], acc[k][3]);
        *reinterpret_cast<float4*>(dst + 4) = make_float4(acc[k][4], acc[k][5], acc[k][6], acc[k][7]);
    }
}

extern "C" void kernel_launch(void* const* d_in, const int* in_sizes, int n_in,
                              void* d_out, int out_size, void* d_ws, size_t ws_size,
                              hipStream_t stream) {
    const float* x    = (const float*)d_in[0];
    const float* Wenc = (const float*)d_in[1];
    const float* benc = (const float*)d_in[2];
    const float* Wmem = (const float*)d_in[3];
    const float* bmem = (const float*)d_in[4];
    const float* Wdec = (const float*)d_in[5];
    const float* bdec = (const float*)d_in[6];
    const float* Wcls = (const float*)d_in[7];
    const float* bcls = (const float*)d_in[8];
    float* out = (float*)d_out;

    k_powA<<<dim3(1), dim3(576), 0, stream>>>(Wmem, out);
    k_enc<<<dim3((B_ * T_) / 128), dim3(128), 0, stream>>>(x, Wenc, benc, bmem, out);
    k_scan<<<dim3(B_), dim3(256), 0, stream>>>(Wmem, out + A16_OFF, Wcls, bcls,
                                               out, out + Z_OFF, out + RECON_FLOATS);
    k_dec<<<dim3((B_ * T_) / 256), dim3(256), 0, stream>>>(Wdec, bdec, out);
}